// Round 18
// baseline (716.511 us; speedup 1.0000x reference)
//
#include <hip/hip_runtime.h>
#include <hip/hip_fp16.h>

#define PN 50000
#define LN 8000
#define HN 8
#define DEGN 64
#define SSN 32

typedef _Float16 half2v __attribute__((ext_vector_type(2)));
typedef unsigned u2v __attribute__((ext_vector_type(2)));
static __device__ __forceinline__ half2v u2h(unsigned u){ half2v h; __builtin_memcpy(&h, &u, 4); return h; }
static __device__ __forceinline__ unsigned pkrtz(float a, float b){
    auto v = __builtin_amdgcn_cvt_pkrtz(a, b); unsigned u; __builtin_memcpy(&u, &v, 4); return u; }
static __device__ __forceinline__ float dpp_x1(float x){
    return __int_as_float(__builtin_amdgcn_update_dpp(0, __float_as_int(x), 0xB1, 0xF, 0xF, true)); }

// cross-half (lane j <-> lane j+32) sum via v_permlane32_swap (VALU, not DS)
static __device__ __forceinline__ float xhalf_sum(float v){
    u2v r = __builtin_amdgcn_permlane32_swap(__float_as_uint(v), __float_as_uint(v), false, false);
    return __uint_as_float(r.x) + __uint_as_float(r.y);
}

// ---- fast-but-accurate nonlinearities ----
static __device__ __forceinline__ float rcp_(float x){ return __builtin_amdgcn_rcpf(x); }
static __device__ __forceinline__ float sig_(float x){ return rcp_(1.0f + __expf(-x)); }
static __device__ __forceinline__ float tanh_(float x){ return 1.0f - 2.0f*rcp_(__expf(2.0f*x) + 1.0f); }

// ws layout (float offsets)
#define OFF_PWHP 0          // path_Wh f16 pairs [q(6)][lane(64)][c(4)] u32  1536
#define OFF_PWXP 3072       // path_Wx f32 [k][j][4]  (k_link_init)      8192
#define OFF_PATH 27648      // path_state (P,32) f32                    1600000
#define OFF_SEQ  1627648    // seq (P,8,16) u32 f16-pairs               6400000
#define OFF_QWX16 14000000  // queue_Wx f16 pairs [m16][j][4] u32       2048
#define OFF_QWH16 14002048
#define OFF_LWX16 14004096
#define OFF_LWH16 14006144
#define OFF_PWX16 14008192  // path_Wx f16 pairs [m32][j][4] u32        4096
#define OFF_QST  14427648   // queue_state (L,16) u32 f16-pairs
#define OFF_LST  14683648   // link_state (L,16) u32 f16-pairs
#define OFF_G    14939648   // G (L,96) planes [{z,r,n}][j]; z,r include bi+bh

// ---------------- weight packing ----------------
__global__ __launch_bounds__(256) void k_pack(
    const float* __restrict__ pWh, const float* __restrict__ pWx,
    const float* __restrict__ qWx, const float* __restrict__ qWh,
    const float* __restrict__ lWx, const float* __restrict__ lWh,
    float* __restrict__ ws)
{
    int i = blockIdx.x*256 + threadIdx.x;
    int i0 = i;
    if (i0 < 3072){
        if (i0 >= 1536) return;
        int q = i0 >> 8, rem = i0 & 255, lane = rem >> 2, c = rem & 3;
        int idx = q*4 + c;
        int g = idx >> 3, m = idx & 7;
        int half16 = (lane >> 5) << 4, j = lane & 31;
        float w0 = pWh[(half16 + 2*m + 0)*96 + g*32 + j];
        float w1 = pWh[(half16 + 2*m + 1)*96 + g*32 + j];
        ((unsigned*)(ws + OFF_PWHP))[i0] = pkrtz(w0, w1);
        return;
    }
    i0 -= 3072;
    if (i0 < 8192){ int k=i0/128, r=i0%128, j=r/4, c=r%4;
        ws[OFF_PWXP+i0] = (c<3)? pWx[k*96 + c*32 + j] : 0.f; return; }
    i0 -= 8192;
    if (i0 < 2048){ int m=i0>>7, rem=i0&127, j=rem>>2, g=rem&3;
        unsigned u=0; if (g<3) u = pkrtz(qWx[(2*m)*96+g*32+j], qWx[(2*m+1)*96+g*32+j]);
        ((unsigned*)(ws+OFF_QWX16))[i0]=u; return; }
    i0 -= 2048;
    if (i0 < 2048){ int m=i0>>7, rem=i0&127, j=rem>>2, g=rem&3;
        unsigned u=0; if (g<3) u = pkrtz(qWh[(2*m)*96+g*32+j], qWh[(2*m+1)*96+g*32+j]);
        ((unsigned*)(ws+OFF_QWH16))[i0]=u; return; }
    i0 -= 2048;
    if (i0 < 2048){ int m=i0>>7, rem=i0&127, j=rem>>2, g=rem&3;
        unsigned u=0; if (g<3) u = pkrtz(lWx[(2*m)*96+g*32+j], lWx[(2*m+1)*96+g*32+j]);
        ((unsigned*)(ws+OFF_LWX16))[i0]=u; return; }
    i0 -= 2048;
    if (i0 < 2048){ int m=i0>>7, rem=i0&127, j=rem>>2, g=rem&3;
        unsigned u=0; if (g<3) u = pkrtz(lWh[(2*m)*96+g*32+j], lWh[(2*m+1)*96+g*32+j]);
        ((unsigned*)(ws+OFF_LWH16))[i0]=u; return; }
    i0 -= 2048;
    if (i0 < 4096){ int m=i0>>7, rem=i0&127, j=rem>>2, g=rem&3;
        unsigned u=0; if (g<3) u = pkrtz(pWx[(2*m)*96+g*32+j], pWx[(2*m+1)*96+g*32+j]);
        ((unsigned*)(ws+OFF_PWX16))[i0]=u; return; }
}

// ---------------- path encoder ----------------
__global__ __launch_bounds__(256, 4) void k_path_init(
    const float* __restrict__ ft, const float* __restrict__ fpk,
    const float* __restrict__ flam, const float* __restrict__ fob,
    const float* __restrict__ fon, const float* __restrict__ foff,
    const int* __restrict__ fdist,
    const float* __restrict__ w1, const float* __restrict__ b1,
    const float* __restrict__ w2, const float* __restrict__ b2,
    float* __restrict__ path_state)
{
    int p = blockIdx.x*256 + threadIdx.x; if (p >= PN) p = PN-1;
    float f[9];
    f[0]=ft[p]; f[1]=fpk[p];
    int dcls = fdist[p];
    f[2] = (dcls==0)?1.f:0.f; f[3]=(dcls==1)?1.f:0.f; f[4]=(dcls==2)?1.f:0.f;
    f[5]=flam[p]; f[6]=fob[p]; f[7]=fon[p]; f[8]=foff[p];
    float h1[SSN];
    #pragma unroll
    for (int j=0;j<SSN;j++){
        float a = b1[j];
        #pragma unroll
        for (int k=0;k<9;k++) a += f[k]*w1[k*SSN+j];
        h1[j] = fmaxf(a, 0.f);
    }
    #pragma unroll
    for (int j=0;j<SSN;j++){
        float a = b2[j];
        #pragma unroll
        for (int k=0;k<SSN;k++) a += h1[k]*w2[k*SSN+j];
        path_state[p*SSN+j] = fmaxf(a, 0.f);
    }
}

// ---------------- link/queue encoders + initial G; states stored f16 ---------
__global__ __launch_bounds__(256) void k_link_init(
    const float* __restrict__ ft, const float* __restrict__ cap,
    const int* __restrict__ p2l, const int* __restrict__ btype,
    const float* __restrict__ lw1, const float* __restrict__ lb1,
    const float* __restrict__ lw2, const float* __restrict__ lb2,
    const float* __restrict__ qw1, const float* __restrict__ qb1,
    const float* __restrict__ qw2, const float* __restrict__ qb2,
    const float* __restrict__ pWxp, const float* __restrict__ pbi,
    const float* __restrict__ pbh,
    unsigned* __restrict__ lstate16, unsigned* __restrict__ qstate16,
    float* __restrict__ G)
{
    __shared__ float tl[4][SSN], tq[4][SSN], x2[4][2*SSN];
    int wid = threadIdx.x >> 6, d = threadIdx.x & 63, j = d & 31;
    int l = blockIdx.x*4 + wid;          // 2000*4 == 8000 exactly
    float s = ft[p2l[(l*DEGN+d)*2]];
    s += __shfl_xor(s, 1);  s += __shfl_xor(s, 2);  s += __shfl_xor(s, 4);
    s += __shfl_xor(s, 8);  s += __shfl_xor(s, 16); s += __shfl_xor(s, 32);
    float load = s / cap[l];
    int bt = btype[l];
    if (d < 32){
        tl[wid][j] = fmaxf(load*lw1[j] + lb1[j], 0.f);
        tq[wid][j] = fmaxf(qw1[bt*SSN+j] + qb1[j], 0.f);
    }
    __syncthreads();
    float al = lb2[j], aq = qb2[j];
    #pragma unroll
    for (int k=0;k<SSN;k++){
        al += tl[wid][k]*lw2[k*SSN+j];
        aq += tq[wid][k]*qw2[k*SSN+j];
    }
    float ls = fmaxf(al, 0.f), qs = fmaxf(aq, 0.f);
    float ls_o = dpp_x1(ls), qs_o = dpp_x1(qs);
    if (d < 32){
        if (!(d & 1)){
            lstate16[l*16 + (j>>1)] = pkrtz(ls, ls_o);
            qstate16[l*16 + (j>>1)] = pkrtz(qs, qs_o);
        }
        x2[wid][j] = qs; x2[wid][SSN+j] = ls;
    }
    __syncthreads();
    float a0=pbi[j]+pbh[j], a1=pbi[SSN+j]+pbh[SSN+j], a2=pbi[2*SSN+j];
    #pragma unroll
    for (int k=0;k<2*SSN;k++){
        float xk = x2[wid][k];
        const float* wv = pWxp + k*128 + j*4;
        a0 += xk*wv[0]; a1 += xk*wv[1]; a2 += xk*wv[2];
    }
    if (d < 32){
        G[l*96 + j] = a0; G[l*96 + SSN + j] = a1; G[l*96 + 2*SSN + j] = a2;
    }
}

// ---------------- path GRU scan: f16 dot2, LDS broadcast (3 DS ops/hop) ------
__global__ __launch_bounds__(256)
void k_path_gru(
    const float* __restrict__ G, const int* __restrict__ l2p,
    const float* __restrict__ Whp, const float* __restrict__ bh,
    float* __restrict__ path_state, unsigned* __restrict__ seq16)
{
    __shared__ unsigned hsh[4][16];
    const int tid  = threadIdx.x;
    const int lane = tid & 63;
    const int j    = lane & 31;
    const int wslot = tid >> 6;
    const int half8 = (lane >> 5) << 3;       // word base: 0 or 8
    const bool wr  = (lane < SSN) && !(lane & 1);
    int p = blockIdx.x*4 + wslot;             // 12500*4 == 50000
    p = __builtin_amdgcn_readfirstlane(p);    // wave-uniform -> SGPR addressing
    unsigned w[24];                           // [g(3)][m(8)] f16 pairs
    {
        const uint4* wp = (const uint4*)Whp;
        #pragma unroll
        for (int q=0;q<6;q++){
            uint4 v = wp[q*64 + lane];
            w[4*q]=v.x; w[4*q+1]=v.y; w[4*q+2]=v.z; w[4*q+3]=v.w;
        }
    }
    const float bn = bh[2*SSN + j];
    const int4 la = *(const int4*)(l2p + p*HN);
    const int4 lb = *(const int4*)(l2p + p*HN + 4);
    float hj = path_state[p*SSN + j];
    {   // publish initial h pairs
        float oth = dpp_x1(hj);
        unsigned pk0 = pkrtz(hj, oth);
        if (wr) hsh[wslot][j>>1] = pk0;
    }
    float cz, cr, cn, nz, nr, nn;
    { const float* g = G + __builtin_amdgcn_readfirstlane(la.x)*96; cz=g[j]; cr=g[SSN+j]; cn=g[2*SSN+j]; }

#define PF(L_) { const float* g = G + __builtin_amdgcn_readfirstlane(L_)*96; nz=g[j]; nr=g[SSN+j]; nn=g[2*SSN+j]; }
#define HOP(T_) { \
    asm volatile("" ::: "memory"); \
    uint4 hv0 = *(const uint4*)&hsh[wslot][half8]; \
    uint4 hv1 = *(const uint4*)&hsh[wslot][half8+4]; \
    float az=0.f, ar=0.f, an=0.f; \
    az = __builtin_amdgcn_fdot2(u2h(hv0.x), u2h(w[ 0]), az, false); \
    ar = __builtin_amdgcn_fdot2(u2h(hv0.x), u2h(w[ 8]), ar, false); \
    an = __builtin_amdgcn_fdot2(u2h(hv0.x), u2h(w[16]), an, false); \
    az = __builtin_amdgcn_fdot2(u2h(hv0.y), u2h(w[ 1]), az, false); \
    ar = __builtin_amdgcn_fdot2(u2h(hv0.y), u2h(w[ 9]), ar, false); \
    an = __builtin_amdgcn_fdot2(u2h(hv0.y), u2h(w[17]), an, false); \
    az = __builtin_amdgcn_fdot2(u2h(hv0.z), u2h(w[ 2]), az, false); \
    ar = __builtin_amdgcn_fdot2(u2h(hv0.z), u2h(w[10]), ar, false); \
    an = __builtin_amdgcn_fdot2(u2h(hv0.z), u2h(w[18]), an, false); \
    az = __builtin_amdgcn_fdot2(u2h(hv0.w), u2h(w[ 3]), az, false); \
    ar = __builtin_amdgcn_fdot2(u2h(hv0.w), u2h(w[11]), ar, false); \
    an = __builtin_amdgcn_fdot2(u2h(hv0.w), u2h(w[19]), an, false); \
    az = __builtin_amdgcn_fdot2(u2h(hv1.x), u2h(w[ 4]), az, false); \
    ar = __builtin_amdgcn_fdot2(u2h(hv1.x), u2h(w[12]), ar, false); \
    an = __builtin_amdgcn_fdot2(u2h(hv1.x), u2h(w[20]), an, false); \
    az = __builtin_amdgcn_fdot2(u2h(hv1.y), u2h(w[ 5]), az, false); \
    ar = __builtin_amdgcn_fdot2(u2h(hv1.y), u2h(w[13]), ar, false); \
    an = __builtin_amdgcn_fdot2(u2h(hv1.y), u2h(w[21]), an, false); \
    az = __builtin_amdgcn_fdot2(u2h(hv1.z), u2h(w[ 6]), az, false); \
    ar = __builtin_amdgcn_fdot2(u2h(hv1.z), u2h(w[14]), ar, false); \
    an = __builtin_amdgcn_fdot2(u2h(hv1.z), u2h(w[22]), an, false); \
    az = __builtin_amdgcn_fdot2(u2h(hv1.w), u2h(w[ 7]), az, false); \
    ar = __builtin_amdgcn_fdot2(u2h(hv1.w), u2h(w[15]), ar, false); \
    an = __builtin_amdgcn_fdot2(u2h(hv1.w), u2h(w[23]), an, false); \
    az = xhalf_sum(az); \
    ar = xhalf_sum(ar); \
    an = xhalf_sum(an); \
    float z = sig_(cz + az); \
    float r = sig_(cr + ar); \
    float n = tanh_(cn + r*(an + bn)); \
    hj = z*hj + (1.0f-z)*n; \
    float oth = dpp_x1(hj); \
    unsigned pk = pkrtz(hj, oth); \
    if (wr){ hsh[wslot][j>>1] = pk; seq16[(p*HN+T_)*16 + (j>>1)] = pk; } \
    cz = nz; cr = nr; cn = nn; }

    PF(la.y) HOP(0)
    PF(la.z) HOP(1)
    PF(la.w) HOP(2)
    PF(lb.x) HOP(3)
    PF(lb.y) HOP(4)
    PF(lb.z) HOP(5)
    PF(lb.w) HOP(6)
    HOP(7)
#undef PF
#undef HOP
    if (lane < SSN) path_state[p*SSN + j] = hj;
}

// ---------------- queue GRU: 2-wave gather + f16 dot2, f16 state -------------
__global__ __launch_bounds__(256) void k_queue_gru(
    const unsigned* __restrict__ seq16, const int* __restrict__ p2l,
    const unsigned* __restrict__ wx16, const unsigned* __restrict__ wh16,
    const float* __restrict__ bi, const float* __restrict__ bhb,
    unsigned* __restrict__ qstate16)
{
    __shared__ float red[2][DEGN][SSN+1];
    __shared__ unsigned xpk_lds[2][16];
    int tid  = threadIdx.x;
    int wv   = tid >> 6;
    int slot = wv >> 1;
    int wp   = wv & 1;
    int lane = tid & 63;
    int r    = (lane & 31) + (wp << 5);
    int half = lane >> 5;
    int l = __builtin_amdgcn_readfirstlane(blockIdx.x*2 + slot);   // 4000*2 == 8000
    int pp  = p2l[(l*DEGN + r)*2 + 0];
    int pos = p2l[(l*DEGN + r)*2 + 1];
    const uint4* row = (const uint4*)(seq16 + (pp*HN + pos - 1)*16 + half*8);
    uint4 v0 = row[0], v1 = row[1];
    float* dst = &red[slot][r][16*half];
    {
        half2v a,b;
        a=u2h(v0.x); b=u2h(v0.y); dst[ 0]=(float)a.x; dst[ 1]=(float)a.y; dst[ 2]=(float)b.x; dst[ 3]=(float)b.y;
        a=u2h(v0.z); b=u2h(v0.w); dst[ 4]=(float)a.x; dst[ 5]=(float)a.y; dst[ 6]=(float)b.x; dst[ 7]=(float)b.y;
        a=u2h(v1.x); b=u2h(v1.y); dst[ 8]=(float)a.x; dst[ 9]=(float)a.y; dst[10]=(float)b.x; dst[11]=(float)b.y;
        a=u2h(v1.z); b=u2h(v1.w); dst[12]=(float)a.x; dst[13]=(float)a.y; dst[14]=(float)b.x; dst[15]=(float)b.y;
    }
    __syncthreads();
    if (wp) return;                          // gather-only wave retires
    int j = lane & 31;
    int base = (lane < 32) ? 0 : 32;
    float xs = 0.f;
    #pragma unroll
    for (int dd=0; dd<32; dd++) xs += red[slot][base+dd][j];
    xs = xhalf_sum(xs);
    {
        float oth = dpp_x1(xs);
        unsigned pkx = pkrtz(xs, oth);
        if (lane < 32 && !(lane & 1)) xpk_lds[slot][j>>1] = pkx;
    }
    // own h row: f16 pairs, wave-uniform address -> scalar loads
    unsigned hpk[16];
    {
        const uint4* h4 = (const uint4*)(qstate16 + l*16);
        #pragma unroll
        for (int q=0;q<4;q++){ uint4 v=h4[q]; hpk[4*q]=v.x; hpk[4*q+1]=v.y; hpk[4*q+2]=v.z; hpk[4*q+3]=v.w; }
    }
    half2v hw = u2h(hpk[j>>1]);
    float hj = (j & 1) ? (float)hw.y : (float)hw.x;
    unsigned xq[16];
    {
        asm volatile("" ::: "memory");
        const uint4* xl = (const uint4*)xpk_lds[slot];
        #pragma unroll
        for (int q=0;q<4;q++){ uint4 v=xl[q]; xq[4*q]=v.x; xq[4*q+1]=v.y; xq[4*q+2]=v.z; xq[4*q+3]=v.w; }
    }
    float az = bi[j] + bhb[j];
    float ar = bi[SSN+j] + bhb[SSN+j];
    float xn = bi[2*SSN+j];
    float hn = bhb[2*SSN+j];
    #pragma unroll
    for (int m=0;m<16;m++){
        uint4 wx4 = ((const uint4*)wx16)[m*32 + j];
        uint4 wh4 = ((const uint4*)wh16)[m*32 + j];
        az = __builtin_amdgcn_fdot2(u2h(xq[m]),  u2h(wx4.x), az, false);
        ar = __builtin_amdgcn_fdot2(u2h(xq[m]),  u2h(wx4.y), ar, false);
        xn = __builtin_amdgcn_fdot2(u2h(xq[m]),  u2h(wx4.z), xn, false);
        az = __builtin_amdgcn_fdot2(u2h(hpk[m]), u2h(wh4.x), az, false);
        ar = __builtin_amdgcn_fdot2(u2h(hpk[m]), u2h(wh4.y), ar, false);
        hn = __builtin_amdgcn_fdot2(u2h(hpk[m]), u2h(wh4.z), hn, false);
    }
    float z = sig_(az), r2 = sig_(ar);
    float n = tanh_(xn + r2*hn);
    float outv = z*hj + (1.0f-z)*n;
    float oth = dpp_x1(outv);
    if (lane < 32 && !(lane & 1))
        qstate16[l*16 + (j>>1)] = pkrtz(outv, oth);
}

// ---------------- link GRU + next-iteration G: f16 state, scalar rows --------
__global__ __launch_bounds__(256) void k_link_gru(
    const unsigned* __restrict__ qstate16, const int* __restrict__ q2l,
    const unsigned* __restrict__ wx16, const unsigned* __restrict__ wh16,
    const float* __restrict__ bi, const float* __restrict__ bhb,
    const unsigned* __restrict__ pwx16, const float* __restrict__ pbi,
    const float* __restrict__ pbh,
    unsigned* __restrict__ lstate16, float* __restrict__ G)
{
    __shared__ unsigned lpk_lds[4][16];
    int wid = threadIdx.x >> 6, d = threadIdx.x & 63, j = d & 31;
    int l = __builtin_amdgcn_readfirstlane(blockIdx.x*4 + wid);
    int src = __builtin_amdgcn_readfirstlane(q2l[l]);
    unsigned xpk[16], hpk[16], qpk[16];
    {
        const uint4* x4 = (const uint4*)(qstate16 + src*16);
        const uint4* h4 = (const uint4*)(lstate16 + l*16);
        const uint4* q4 = (const uint4*)(qstate16 + l*16);
        #pragma unroll
        for (int q=0;q<4;q++){
            uint4 a=x4[q]; xpk[4*q]=a.x; xpk[4*q+1]=a.y; xpk[4*q+2]=a.z; xpk[4*q+3]=a.w;
            uint4 b=h4[q]; hpk[4*q]=b.x; hpk[4*q+1]=b.y; hpk[4*q+2]=b.z; hpk[4*q+3]=b.w;
            uint4 c=q4[q]; qpk[4*q]=c.x; qpk[4*q+1]=c.y; qpk[4*q+2]=c.z; qpk[4*q+3]=c.w;
        }
    }
    half2v hw = u2h(hpk[j>>1]);
    float hj = (j & 1) ? (float)hw.y : (float)hw.x;
    float az = bi[j]+bhb[j], ar = bi[SSN+j]+bhb[SSN+j];
    float xn = bi[2*SSN+j], hn = bhb[2*SSN+j];
    #pragma unroll
    for (int m=0;m<16;m++){
        uint4 wx4 = ((const uint4*)wx16)[m*32 + j];
        uint4 wh4 = ((const uint4*)wh16)[m*32 + j];
        az = __builtin_amdgcn_fdot2(u2h(xpk[m]), u2h(wx4.x), az, false);
        ar = __builtin_amdgcn_fdot2(u2h(xpk[m]), u2h(wx4.y), ar, false);
        xn = __builtin_amdgcn_fdot2(u2h(xpk[m]), u2h(wx4.z), xn, false);
        az = __builtin_amdgcn_fdot2(u2h(hpk[m]), u2h(wh4.x), az, false);
        ar = __builtin_amdgcn_fdot2(u2h(hpk[m]), u2h(wh4.y), ar, false);
        hn = __builtin_amdgcn_fdot2(u2h(hpk[m]), u2h(wh4.z), hn, false);
    }
    float z = sig_(az), r = sig_(ar);
    float n = tanh_(xn + r*hn);
    float outv = z*hj + (1.0f-z)*n;
    {
        float oth = dpp_x1(outv);
        unsigned pko = pkrtz(outv, oth);
        if (d < 32 && !(d & 1)){ lstate16[l*16 + (j>>1)] = pko; lpk_lds[wid][j>>1] = pko; }
    }
    unsigned lpk[16];
    {
        asm volatile("" ::: "memory");
        const uint4* ll = (const uint4*)lpk_lds[wid];
        #pragma unroll
        for (int q=0;q<4;q++){ uint4 v=ll[q]; lpk[4*q]=v.x; lpk[4*q+1]=v.y; lpk[4*q+2]=v.z; lpk[4*q+3]=v.w; }
    }
    float a0 = pbi[j]+pbh[j], a1 = pbi[SSN+j]+pbh[SSN+j], a2 = pbi[2*SSN+j];
    #pragma unroll
    for (int m=0;m<32;m++){
        uint4 wv4 = ((const uint4*)pwx16)[m*32 + j];
        unsigned xm = (m < 16) ? qpk[m] : lpk[m-16];
        a0 = __builtin_amdgcn_fdot2(u2h(xm), u2h(wv4.x), a0, false);
        a1 = __builtin_amdgcn_fdot2(u2h(xm), u2h(wv4.y), a1, false);
        a2 = __builtin_amdgcn_fdot2(u2h(xm), u2h(wv4.z), a2, false);
    }
    if (d < 32){
        G[l*96 + j] = a0; G[l*96 + SSN + j] = a1; G[l*96 + 2*SSN + j] = a2;
    }
}

// ---------------- readout: thread per (path, hop), f16 seq in ----------------
__global__ __launch_bounds__(256, 4) void k_readout(
    const unsigned* __restrict__ seq16, const int* __restrict__ l2p,
    const float* __restrict__ cap, const float* __restrict__ ft,
    const float* __restrict__ fpk,
    const float* __restrict__ w1, const float* __restrict__ b1,
    const float* __restrict__ w2, const float* __restrict__ b2,
    const float* __restrict__ w3, const float* __restrict__ b3,
    float* __restrict__ out)
{
    int g = blockIdx.x*256 + threadIdx.x;
    int p = g >> 3, t = g & 7;
    if (p >= PN) p = PN-1;               // tail: duplicate same-value writes, benign
    int lk = l2p[p*HN + t];
    const uint4* s4 = (const uint4*)(seq16 + (p*HN+t)*16);
    float sv[SSN];
    #pragma unroll
    for (int q=0;q<4;q++){
        uint4 v = s4[q];
        half2v a=u2h(v.x), b=u2h(v.y), c=u2h(v.z), e=u2h(v.w);
        sv[8*q+0]=(float)a.x; sv[8*q+1]=(float)a.y;
        sv[8*q+2]=(float)b.x; sv[8*q+3]=(float)b.y;
        sv[8*q+4]=(float)c.x; sv[8*q+5]=(float)c.y;
        sv[8*q+6]=(float)e.x; sv[8*q+7]=(float)e.y;
    }
    float h1[16];
    #pragma unroll
    for (int j=0;j<16;j++) h1[j] = b1[j];
    #pragma unroll
    for (int k=0;k<SSN;k++){
        float vk = sv[k];
        #pragma unroll
        for (int j=0;j<16;j++) h1[j] += vk*w1[k*16+j];
    }
    #pragma unroll
    for (int j=0;j<16;j++) h1[j] = fmaxf(h1[j], 0.f);
    float h2[16];
    #pragma unroll
    for (int j=0;j<16;j++) h2[j] = b2[j];
    #pragma unroll
    for (int k=0;k<16;k++){
        float hk = h1[k];
        #pragma unroll
        for (int j=0;j<16;j++) h2[j] += hk*w2[k*16+j];
    }
    float occ = b3[0];
    #pragma unroll
    for (int k=0;k<16;k++) occ += fmaxf(h2[k], 0.f)*w3[k];
    float icg = rcp_(cap[lk]) * 1e-9f;
    float qd  = occ * icg;
    float inv = icg;
    qd  += __shfl_xor(qd, 1);  inv += __shfl_xor(inv, 1);
    qd  += __shfl_xor(qd, 2);  inv += __shfl_xor(inv, 2);
    qd  += __shfl_xor(qd, 4);  inv += __shfl_xor(inv, 4);
    if ((threadIdx.x & 7) == 0)
        out[p] = qd + ft[p]*rcp_(fpk[p])*inv;
}

extern "C" void kernel_launch(void* const* d_in, const int* in_sizes, int n_in,
                              void* d_out, int out_size, void* d_ws, size_t ws_size,
                              hipStream_t stream)
{
    (void)in_sizes; (void)n_in; (void)out_size; (void)ws_size;
    const float* ft    = (const float*)d_in[0];
    const float* fpk   = (const float*)d_in[1];
    const float* flam  = (const float*)d_in[2];
    const float* fob   = (const float*)d_in[3];
    const float* fon   = (const float*)d_in[4];
    const float* foff  = (const float*)d_in[5];
    const float* cap   = (const float*)d_in[6];
    const float* pe_w1 = (const float*)d_in[7];
    const float* pe_b1 = (const float*)d_in[8];
    const float* pe_w2 = (const float*)d_in[9];
    const float* pe_b2 = (const float*)d_in[10];
    const float* le_w1 = (const float*)d_in[11];
    const float* le_b1 = (const float*)d_in[12];
    const float* le_w2 = (const float*)d_in[13];
    const float* le_b2 = (const float*)d_in[14];
    const float* qe_w1 = (const float*)d_in[15];
    const float* qe_b1 = (const float*)d_in[16];
    const float* qe_w2 = (const float*)d_in[17];
    const float* qe_b2 = (const float*)d_in[18];
    const float* pWx   = (const float*)d_in[19];
    const float* pWh   = (const float*)d_in[20];
    const float* pbi   = (const float*)d_in[21];
    const float* pbh   = (const float*)d_in[22];
    const float* qWx   = (const float*)d_in[23];
    const float* qWh   = (const float*)d_in[24];
    const float* qbi   = (const float*)d_in[25];
    const float* qbh   = (const float*)d_in[26];
    const float* lWx   = (const float*)d_in[27];
    const float* lWh   = (const float*)d_in[28];
    const float* lbi   = (const float*)d_in[29];
    const float* lbh   = (const float*)d_in[30];
    const float* ro_w1 = (const float*)d_in[31];
    const float* ro_b1 = (const float*)d_in[32];
    const float* ro_w2 = (const float*)d_in[33];
    const float* ro_b2 = (const float*)d_in[34];
    const float* ro_w3 = (const float*)d_in[35];
    const float* ro_b3 = (const float*)d_in[36];
    const int* fdist = (const int*)d_in[37];
    const int* btype = (const int*)d_in[38];
    const int* l2p   = (const int*)d_in[39];
    const int* p2l   = (const int*)d_in[40];
    const int* q2l   = (const int*)d_in[41];

    float* ws = (float*)d_ws;
    float* pWhp = ws + OFF_PWHP;
    float* pWxp = ws + OFF_PWXP;
    float* path_state  = ws + OFF_PATH;
    unsigned* seq16    = (unsigned*)(ws + OFF_SEQ);
    unsigned* qwx16    = (unsigned*)(ws + OFF_QWX16);
    unsigned* qwh16    = (unsigned*)(ws + OFF_QWH16);
    unsigned* lwx16    = (unsigned*)(ws + OFF_LWX16);
    unsigned* lwh16    = (unsigned*)(ws + OFF_LWH16);
    unsigned* pwx16    = (unsigned*)(ws + OFF_PWX16);
    unsigned* qstate16 = (unsigned*)(ws + OFF_QST);
    unsigned* lstate16 = (unsigned*)(ws + OFF_LST);
    float* G           = ws + OFF_G;

    k_pack<<<156, 256, 0, stream>>>(pWh, pWx, qWx, qWh, lWx, lWh, ws);
    k_path_init<<<(PN+255)/256, 256, 0, stream>>>(ft, fpk, flam, fob, fon, foff, fdist,
                                                  pe_w1, pe_b1, pe_w2, pe_b2, path_state);
    k_link_init<<<LN/4, 256, 0, stream>>>(ft, cap, p2l, btype,
                                          le_w1, le_b1, le_w2, le_b2,
                                          qe_w1, qe_b1, qe_w2, qe_b2,
                                          pWxp, pbi, pbh, lstate16, qstate16, G);
    for (int it = 0; it < 8; ++it){
        k_path_gru<<<PN/4, 256, 0, stream>>>(G, l2p, pWhp, pbh, path_state, seq16);
        k_queue_gru<<<LN/2, 256, 0, stream>>>(seq16, p2l, qwx16, qwh16, qbi, qbh, qstate16);
        k_link_gru<<<LN/4, 256, 0, stream>>>(qstate16, q2l, lwx16, lwh16, lbi, lbh,
                                             pwx16, pbi, pbh, lstate16, G);
    }
    k_readout<<<(PN*HN+255)/256, 256, 0, stream>>>(seq16, l2p, cap, ft, fpk,
                                                   ro_w1, ro_b1, ro_w2, ro_b2, ro_w3, ro_b3,
                                                   (float*)d_out);
}

// Round 19
// 668.630 us; speedup vs baseline: 1.0716x; 1.0716x over previous
//
#include <hip/hip_runtime.h>
#include <hip/hip_fp16.h>

#define PN 50000
#define LN 8000
#define HN 8
#define DEGN 64
#define SSN 32

typedef _Float16 half2v __attribute__((ext_vector_type(2)));
typedef unsigned u2v __attribute__((ext_vector_type(2)));
static __device__ __forceinline__ half2v u2h(unsigned u){ half2v h; __builtin_memcpy(&h, &u, 4); return h; }
static __device__ __forceinline__ unsigned pkrtz(float a, float b){
    auto v = __builtin_amdgcn_cvt_pkrtz(a, b); unsigned u; __builtin_memcpy(&u, &v, 4); return u; }
static __device__ __forceinline__ float dpp_x1(float x){
    return __int_as_float(__builtin_amdgcn_update_dpp(0, __float_as_int(x), 0xB1, 0xF, 0xF, true)); }

// cross-half (lane j <-> lane j+32) sum via v_permlane32_swap (VALU, not DS)
static __device__ __forceinline__ float xhalf_sum(float v){
    u2v r = __builtin_amdgcn_permlane32_swap(__float_as_uint(v), __float_as_uint(v), false, false);
    return __uint_as_float(r.x) + __uint_as_float(r.y);
}

// ---- fast-but-accurate nonlinearities ----
static __device__ __forceinline__ float rcp_(float x){ return __builtin_amdgcn_rcpf(x); }
static __device__ __forceinline__ float sig_(float x){ return rcp_(1.0f + __expf(-x)); }
static __device__ __forceinline__ float tanh_(float x){ return 1.0f - 2.0f*rcp_(__expf(2.0f*x) + 1.0f); }

// ws layout (float offsets)
#define OFF_PWHP 0          // path_Wh f16 pairs [q(6)][lane(64)][c(4)] u32  1536
#define OFF_PATH 27648      // path_state (P,32) f32                    1600000
#define OFF_SEQ  1627648    // seq (P,8,16) u32 f16-pairs               6400000
#define OFF_QWX16 14000000  // queue_Wx f16 pairs [m16][j][4] u32       2048
#define OFF_QWH16 14002048
#define OFF_LWX16 14004096
#define OFF_LWH16 14006144
#define OFF_PWX16 14008192  // path_Wx f16 pairs [m32][j][4] u32        4096
#define OFF_QST  14427648   // queue_state (L,16) u32 f16-pairs
#define OFF_LST  14683648   // link_state (L,16) u32 f16-pairs
#define OFF_G    14939648   // G (L,96) planes [{z,r,n}][j]; z,r include bi+bh

// ---------------- fused startup: pack + path_init + link_init ----------------
// blocks [0,54): weight packing; [54,250): path encoder; [250,2250): link/queue
// encoders + initial G. No intra-kernel dependencies (link_init reads raw pWx).
__global__ __launch_bounds__(256) void k_startup(
    // pack inputs
    const float* __restrict__ pWh, const float* __restrict__ pWx,
    const float* __restrict__ qWx, const float* __restrict__ qWh,
    const float* __restrict__ lWx, const float* __restrict__ lWh,
    float* __restrict__ ws,
    // path_init inputs
    const float* __restrict__ ft, const float* __restrict__ fpk,
    const float* __restrict__ flam, const float* __restrict__ fob,
    const float* __restrict__ fon, const float* __restrict__ foff,
    const int* __restrict__ fdist,
    const float* __restrict__ pe_w1, const float* __restrict__ pe_b1,
    const float* __restrict__ pe_w2, const float* __restrict__ pe_b2,
    float* __restrict__ path_state,
    // link_init inputs
    const float* __restrict__ cap,
    const int* __restrict__ p2l, const int* __restrict__ btype,
    const float* __restrict__ lw1, const float* __restrict__ lb1,
    const float* __restrict__ lw2, const float* __restrict__ lb2,
    const float* __restrict__ qw1, const float* __restrict__ qb1,
    const float* __restrict__ qw2, const float* __restrict__ qb2,
    const float* __restrict__ pbi, const float* __restrict__ pbh,
    unsigned* __restrict__ lstate16, unsigned* __restrict__ qstate16,
    float* __restrict__ G)
{
    __shared__ float tl[4][SSN], tq[4][SSN], x2[4][2*SSN];
    int b = blockIdx.x;
    if (b < 54){
        int i0 = b*256 + threadIdx.x;
        if (i0 < 1536){
            int q = i0 >> 8, rem = i0 & 255, lane = rem >> 2, c = rem & 3;
            int idx = q*4 + c;
            int g = idx >> 3, m = idx & 7;
            int half16 = (lane >> 5) << 4, j = lane & 31;
            float w0 = pWh[(half16 + 2*m + 0)*96 + g*32 + j];
            float w1 = pWh[(half16 + 2*m + 1)*96 + g*32 + j];
            ((unsigned*)(ws + OFF_PWHP))[i0] = pkrtz(w0, w1);
            return;
        }
        i0 -= 1536;
        if (i0 < 2048){ int m=i0>>7, rem=i0&127, j=rem>>2, g=rem&3;
            unsigned u=0; if (g<3) u = pkrtz(qWx[(2*m)*96+g*32+j], qWx[(2*m+1)*96+g*32+j]);
            ((unsigned*)(ws+OFF_QWX16))[i0]=u; return; }
        i0 -= 2048;
        if (i0 < 2048){ int m=i0>>7, rem=i0&127, j=rem>>2, g=rem&3;
            unsigned u=0; if (g<3) u = pkrtz(qWh[(2*m)*96+g*32+j], qWh[(2*m+1)*96+g*32+j]);
            ((unsigned*)(ws+OFF_QWH16))[i0]=u; return; }
        i0 -= 2048;
        if (i0 < 2048){ int m=i0>>7, rem=i0&127, j=rem>>2, g=rem&3;
            unsigned u=0; if (g<3) u = pkrtz(lWx[(2*m)*96+g*32+j], lWx[(2*m+1)*96+g*32+j]);
            ((unsigned*)(ws+OFF_LWX16))[i0]=u; return; }
        i0 -= 2048;
        if (i0 < 2048){ int m=i0>>7, rem=i0&127, j=rem>>2, g=rem&3;
            unsigned u=0; if (g<3) u = pkrtz(lWh[(2*m)*96+g*32+j], lWh[(2*m+1)*96+g*32+j]);
            ((unsigned*)(ws+OFF_LWH16))[i0]=u; return; }
        i0 -= 2048;
        if (i0 < 4096){ int m=i0>>7, rem=i0&127, j=rem>>2, g=rem&3;
            unsigned u=0; if (g<3) u = pkrtz(pWx[(2*m)*96+g*32+j], pWx[(2*m+1)*96+g*32+j]);
            ((unsigned*)(ws+OFF_PWX16))[i0]=u; return; }
        return;
    }
    if (b < 250){
        int p = (b-54)*256 + threadIdx.x; if (p >= PN) p = PN-1;
        float f[9];
        f[0]=ft[p]; f[1]=fpk[p];
        int dcls = fdist[p];
        f[2] = (dcls==0)?1.f:0.f; f[3]=(dcls==1)?1.f:0.f; f[4]=(dcls==2)?1.f:0.f;
        f[5]=flam[p]; f[6]=fob[p]; f[7]=fon[p]; f[8]=foff[p];
        float h1[SSN];
        #pragma unroll
        for (int j=0;j<SSN;j++){
            float a = pe_b1[j];
            #pragma unroll
            for (int k=0;k<9;k++) a += f[k]*pe_w1[k*SSN+j];
            h1[j] = fmaxf(a, 0.f);
        }
        #pragma unroll
        for (int j=0;j<SSN;j++){
            float a = pe_b2[j];
            #pragma unroll
            for (int k=0;k<SSN;k++) a += h1[k]*pe_w2[k*SSN+j];
            path_state[p*SSN+j] = fmaxf(a, 0.f);
        }
        return;
    }
    {
        int wid = threadIdx.x >> 6, d = threadIdx.x & 63, j = d & 31;
        int l = (b-250)*4 + wid;         // 2000*4 == 8000 exactly
        float s = ft[p2l[(l*DEGN+d)*2]];
        s += __shfl_xor(s, 1);  s += __shfl_xor(s, 2);  s += __shfl_xor(s, 4);
        s += __shfl_xor(s, 8);  s += __shfl_xor(s, 16); s += __shfl_xor(s, 32);
        float load = s / cap[l];
        int bt = btype[l];
        if (d < 32){
            tl[wid][j] = fmaxf(load*lw1[j] + lb1[j], 0.f);
            tq[wid][j] = fmaxf(qw1[bt*SSN+j] + qb1[j], 0.f);
        }
        __syncthreads();
        float al = lb2[j], aq = qb2[j];
        #pragma unroll
        for (int k=0;k<SSN;k++){
            al += tl[wid][k]*lw2[k*SSN+j];
            aq += tq[wid][k]*qw2[k*SSN+j];
        }
        float ls = fmaxf(al, 0.f), qs = fmaxf(aq, 0.f);
        float ls_o = dpp_x1(ls), qs_o = dpp_x1(qs);
        if (d < 32){
            if (!(d & 1)){
                lstate16[l*16 + (j>>1)] = pkrtz(ls, ls_o);
                qstate16[l*16 + (j>>1)] = pkrtz(qs, qs_o);
            }
            x2[wid][j] = qs; x2[wid][SSN+j] = ls;
        }
        __syncthreads();
        float a0=pbi[j]+pbh[j], a1=pbi[SSN+j]+pbh[SSN+j], a2=pbi[2*SSN+j];
        #pragma unroll
        for (int k=0;k<2*SSN;k++){
            float xk = x2[wid][k];
            a0 += xk*pWx[k*96 + j];
            a1 += xk*pWx[k*96 + SSN + j];
            a2 += xk*pWx[k*96 + 2*SSN + j];
        }
        if (d < 32){
            G[l*96 + j] = a0; G[l*96 + SSN + j] = a1; G[l*96 + 2*SSN + j] = a2;
        }
    }
}

// ---------------- path GRU scan: f16 dot2, LDS broadcast (3 DS ops/hop) ------
__global__ __launch_bounds__(256)
void k_path_gru(
    const float* __restrict__ G, const int* __restrict__ l2p,
    const float* __restrict__ Whp, const float* __restrict__ bh,
    float* __restrict__ path_state, unsigned* __restrict__ seq16)
{
    __shared__ unsigned hsh[4][16];
    const int tid  = threadIdx.x;
    const int lane = tid & 63;
    const int j    = lane & 31;
    const int wslot = tid >> 6;
    const int half8 = (lane >> 5) << 3;       // word base: 0 or 8
    const bool wr  = (lane < SSN) && !(lane & 1);
    int p = blockIdx.x*4 + wslot;             // 12500*4 == 50000
    p = __builtin_amdgcn_readfirstlane(p);    // wave-uniform -> SGPR addressing
    unsigned w[24];                           // [g(3)][m(8)] f16 pairs
    {
        const uint4* wp = (const uint4*)Whp;
        #pragma unroll
        for (int q=0;q<6;q++){
            uint4 v = wp[q*64 + lane];
            w[4*q]=v.x; w[4*q+1]=v.y; w[4*q+2]=v.z; w[4*q+3]=v.w;
        }
    }
    const float bn = bh[2*SSN + j];
    const int4 la = *(const int4*)(l2p + p*HN);
    const int4 lb = *(const int4*)(l2p + p*HN + 4);
    float hj = path_state[p*SSN + j];
    {   // publish initial h pairs
        float oth = dpp_x1(hj);
        unsigned pk0 = pkrtz(hj, oth);
        if (wr) hsh[wslot][j>>1] = pk0;
    }
    float cz, cr, cn, nz, nr, nn;
    { const float* g = G + __builtin_amdgcn_readfirstlane(la.x)*96; cz=g[j]; cr=g[SSN+j]; cn=g[2*SSN+j]; }

#define PF(L_) { const float* g = G + __builtin_amdgcn_readfirstlane(L_)*96; nz=g[j]; nr=g[SSN+j]; nn=g[2*SSN+j]; }
#define HOP(T_) { \
    asm volatile("" ::: "memory"); \
    uint4 hv0 = *(const uint4*)&hsh[wslot][half8]; \
    uint4 hv1 = *(const uint4*)&hsh[wslot][half8+4]; \
    float az=0.f, ar=0.f, an=0.f; \
    az = __builtin_amdgcn_fdot2(u2h(hv0.x), u2h(w[ 0]), az, false); \
    ar = __builtin_amdgcn_fdot2(u2h(hv0.x), u2h(w[ 8]), ar, false); \
    an = __builtin_amdgcn_fdot2(u2h(hv0.x), u2h(w[16]), an, false); \
    az = __builtin_amdgcn_fdot2(u2h(hv0.y), u2h(w[ 1]), az, false); \
    ar = __builtin_amdgcn_fdot2(u2h(hv0.y), u2h(w[ 9]), ar, false); \
    an = __builtin_amdgcn_fdot2(u2h(hv0.y), u2h(w[17]), an, false); \
    az = __builtin_amdgcn_fdot2(u2h(hv0.z), u2h(w[ 2]), az, false); \
    ar = __builtin_amdgcn_fdot2(u2h(hv0.z), u2h(w[10]), ar, false); \
    an = __builtin_amdgcn_fdot2(u2h(hv0.z), u2h(w[18]), an, false); \
    az = __builtin_amdgcn_fdot2(u2h(hv0.w), u2h(w[ 3]), az, false); \
    ar = __builtin_amdgcn_fdot2(u2h(hv0.w), u2h(w[11]), ar, false); \
    an = __builtin_amdgcn_fdot2(u2h(hv0.w), u2h(w[19]), an, false); \
    az = __builtin_amdgcn_fdot2(u2h(hv1.x), u2h(w[ 4]), az, false); \
    ar = __builtin_amdgcn_fdot2(u2h(hv1.x), u2h(w[12]), ar, false); \
    an = __builtin_amdgcn_fdot2(u2h(hv1.x), u2h(w[20]), an, false); \
    az = __builtin_amdgcn_fdot2(u2h(hv1.y), u2h(w[ 5]), az, false); \
    ar = __builtin_amdgcn_fdot2(u2h(hv1.y), u2h(w[13]), ar, false); \
    an = __builtin_amdgcn_fdot2(u2h(hv1.y), u2h(w[21]), an, false); \
    az = __builtin_amdgcn_fdot2(u2h(hv1.z), u2h(w[ 6]), az, false); \
    ar = __builtin_amdgcn_fdot2(u2h(hv1.z), u2h(w[14]), ar, false); \
    an = __builtin_amdgcn_fdot2(u2h(hv1.z), u2h(w[22]), an, false); \
    az = __builtin_amdgcn_fdot2(u2h(hv1.w), u2h(w[ 7]), az, false); \
    ar = __builtin_amdgcn_fdot2(u2h(hv1.w), u2h(w[15]), ar, false); \
    an = __builtin_amdgcn_fdot2(u2h(hv1.w), u2h(w[23]), an, false); \
    az = xhalf_sum(az); \
    ar = xhalf_sum(ar); \
    an = xhalf_sum(an); \
    float z = sig_(cz + az); \
    float r = sig_(cr + ar); \
    float n = tanh_(cn + r*(an + bn)); \
    hj = z*hj + (1.0f-z)*n; \
    float oth = dpp_x1(hj); \
    unsigned pk = pkrtz(hj, oth); \
    if (wr){ hsh[wslot][j>>1] = pk; seq16[(p*HN+T_)*16 + (j>>1)] = pk; } \
    cz = nz; cr = nr; cn = nn; }

    PF(la.y) HOP(0)
    PF(la.z) HOP(1)
    PF(la.w) HOP(2)
    PF(lb.x) HOP(3)
    PF(lb.y) HOP(4)
    PF(lb.z) HOP(5)
    PF(lb.w) HOP(6)
    HOP(7)
#undef PF
#undef HOP
    if (lane < SSN) path_state[p*SSN + j] = hj;
}

// ---------------- queue GRU: 2-wave gather + f16 dot2, f16 state -------------
__global__ __launch_bounds__(256) void k_queue_gru(
    const unsigned* __restrict__ seq16, const int* __restrict__ p2l,
    const unsigned* __restrict__ wx16, const unsigned* __restrict__ wh16,
    const float* __restrict__ bi, const float* __restrict__ bhb,
    unsigned* __restrict__ qstate16)
{
    __shared__ float red[2][DEGN][SSN+1];
    __shared__ unsigned xpk_lds[2][16];
    int tid  = threadIdx.x;
    int wv   = tid >> 6;
    int slot = wv >> 1;
    int wp   = wv & 1;
    int lane = tid & 63;
    int r    = (lane & 31) + (wp << 5);
    int half = lane >> 5;
    int l = __builtin_amdgcn_readfirstlane(blockIdx.x*2 + slot);   // 4000*2 == 8000
    int pp  = p2l[(l*DEGN + r)*2 + 0];
    int pos = p2l[(l*DEGN + r)*2 + 1];
    const uint4* row = (const uint4*)(seq16 + (pp*HN + pos - 1)*16 + half*8);
    uint4 v0 = row[0], v1 = row[1];
    float* dst = &red[slot][r][16*half];
    {
        half2v a,b;
        a=u2h(v0.x); b=u2h(v0.y); dst[ 0]=(float)a.x; dst[ 1]=(float)a.y; dst[ 2]=(float)b.x; dst[ 3]=(float)b.y;
        a=u2h(v0.z); b=u2h(v0.w); dst[ 4]=(float)a.x; dst[ 5]=(float)a.y; dst[ 6]=(float)b.x; dst[ 7]=(float)b.y;
        a=u2h(v1.x); b=u2h(v1.y); dst[ 8]=(float)a.x; dst[ 9]=(float)a.y; dst[10]=(float)b.x; dst[11]=(float)b.y;
        a=u2h(v1.z); b=u2h(v1.w); dst[12]=(float)a.x; dst[13]=(float)a.y; dst[14]=(float)b.x; dst[15]=(float)b.y;
    }
    __syncthreads();
    if (wp) return;                          // gather-only wave retires
    int j = lane & 31;
    int base = (lane < 32) ? 0 : 32;
    float xs = 0.f;
    #pragma unroll
    for (int dd=0; dd<32; dd++) xs += red[slot][base+dd][j];
    xs = xhalf_sum(xs);
    {
        float oth = dpp_x1(xs);
        unsigned pkx = pkrtz(xs, oth);
        if (lane < 32 && !(lane & 1)) xpk_lds[slot][j>>1] = pkx;
    }
    // own h row: f16 pairs, wave-uniform address -> scalar loads
    unsigned hpk[16];
    {
        const uint4* h4 = (const uint4*)(qstate16 + l*16);
        #pragma unroll
        for (int q=0;q<4;q++){ uint4 v=h4[q]; hpk[4*q]=v.x; hpk[4*q+1]=v.y; hpk[4*q+2]=v.z; hpk[4*q+3]=v.w; }
    }
    half2v hw = u2h(hpk[j>>1]);
    float hj = (j & 1) ? (float)hw.y : (float)hw.x;
    unsigned xq[16];
    {
        asm volatile("" ::: "memory");
        const uint4* xl = (const uint4*)xpk_lds[slot];
        #pragma unroll
        for (int q=0;q<4;q++){ uint4 v=xl[q]; xq[4*q]=v.x; xq[4*q+1]=v.y; xq[4*q+2]=v.z; xq[4*q+3]=v.w; }
    }
    float az = bi[j] + bhb[j];
    float ar = bi[SSN+j] + bhb[SSN+j];
    float xn = bi[2*SSN+j];
    float hn = bhb[2*SSN+j];
    #pragma unroll
    for (int m=0;m<16;m++){
        uint4 wx4 = ((const uint4*)wx16)[m*32 + j];
        uint4 wh4 = ((const uint4*)wh16)[m*32 + j];
        az = __builtin_amdgcn_fdot2(u2h(xq[m]),  u2h(wx4.x), az, false);
        ar = __builtin_amdgcn_fdot2(u2h(xq[m]),  u2h(wx4.y), ar, false);
        xn = __builtin_amdgcn_fdot2(u2h(xq[m]),  u2h(wx4.z), xn, false);
        az = __builtin_amdgcn_fdot2(u2h(hpk[m]), u2h(wh4.x), az, false);
        ar = __builtin_amdgcn_fdot2(u2h(hpk[m]), u2h(wh4.y), ar, false);
        hn = __builtin_amdgcn_fdot2(u2h(hpk[m]), u2h(wh4.z), hn, false);
    }
    float z = sig_(az), r2 = sig_(ar);
    float n = tanh_(xn + r2*hn);
    float outv = z*hj + (1.0f-z)*n;
    float oth = dpp_x1(outv);
    if (lane < 32 && !(lane & 1))
        qstate16[l*16 + (j>>1)] = pkrtz(outv, oth);
}

// ---------------- link GRU + next-iteration G: f16 state, scalar rows --------
__global__ __launch_bounds__(256) void k_link_gru(
    const unsigned* __restrict__ qstate16, const int* __restrict__ q2l,
    const unsigned* __restrict__ wx16, const unsigned* __restrict__ wh16,
    const float* __restrict__ bi, const float* __restrict__ bhb,
    const unsigned* __restrict__ pwx16, const float* __restrict__ pbi,
    const float* __restrict__ pbh,
    unsigned* __restrict__ lstate16, float* __restrict__ G)
{
    __shared__ unsigned lpk_lds[4][16];
    int wid = threadIdx.x >> 6, d = threadIdx.x & 63, j = d & 31;
    int l = __builtin_amdgcn_readfirstlane(blockIdx.x*4 + wid);
    int src = __builtin_amdgcn_readfirstlane(q2l[l]);
    unsigned xpk[16], hpk[16], qpk[16];
    {
        const uint4* x4 = (const uint4*)(qstate16 + src*16);
        const uint4* h4 = (const uint4*)(lstate16 + l*16);
        const uint4* q4 = (const uint4*)(qstate16 + l*16);
        #pragma unroll
        for (int q=0;q<4;q++){
            uint4 a=x4[q]; xpk[4*q]=a.x; xpk[4*q+1]=a.y; xpk[4*q+2]=a.z; xpk[4*q+3]=a.w;
            uint4 b=h4[q]; hpk[4*q]=b.x; hpk[4*q+1]=b.y; hpk[4*q+2]=b.z; hpk[4*q+3]=b.w;
            uint4 c=q4[q]; qpk[4*q]=c.x; qpk[4*q+1]=c.y; qpk[4*q+2]=c.z; qpk[4*q+3]=c.w;
        }
    }
    half2v hw = u2h(hpk[j>>1]);
    float hj = (j & 1) ? (float)hw.y : (float)hw.x;
    float az = bi[j]+bhb[j], ar = bi[SSN+j]+bhb[SSN+j];
    float xn = bi[2*SSN+j], hn = bhb[2*SSN+j];
    #pragma unroll
    for (int m=0;m<16;m++){
        uint4 wx4 = ((const uint4*)wx16)[m*32 + j];
        uint4 wh4 = ((const uint4*)wh16)[m*32 + j];
        az = __builtin_amdgcn_fdot2(u2h(xpk[m]), u2h(wx4.x), az, false);
        ar = __builtin_amdgcn_fdot2(u2h(xpk[m]), u2h(wx4.y), ar, false);
        xn = __builtin_amdgcn_fdot2(u2h(xpk[m]), u2h(wx4.z), xn, false);
        az = __builtin_amdgcn_fdot2(u2h(hpk[m]), u2h(wh4.x), az, false);
        ar = __builtin_amdgcn_fdot2(u2h(hpk[m]), u2h(wh4.y), ar, false);
        hn = __builtin_amdgcn_fdot2(u2h(hpk[m]), u2h(wh4.z), hn, false);
    }
    float z = sig_(az), r = sig_(ar);
    float n = tanh_(xn + r*hn);
    float outv = z*hj + (1.0f-z)*n;
    {
        float oth = dpp_x1(outv);
        unsigned pko = pkrtz(outv, oth);
        if (d < 32 && !(d & 1)){ lstate16[l*16 + (j>>1)] = pko; lpk_lds[wid][j>>1] = pko; }
    }
    unsigned lpk[16];
    {
        asm volatile("" ::: "memory");
        const uint4* ll = (const uint4*)lpk_lds[wid];
        #pragma unroll
        for (int q=0;q<4;q++){ uint4 v=ll[q]; lpk[4*q]=v.x; lpk[4*q+1]=v.y; lpk[4*q+2]=v.z; lpk[4*q+3]=v.w; }
    }
    float a0 = pbi[j]+pbh[j], a1 = pbi[SSN+j]+pbh[SSN+j], a2 = pbi[2*SSN+j];
    #pragma unroll
    for (int m=0;m<32;m++){
        uint4 wv4 = ((const uint4*)pwx16)[m*32 + j];
        unsigned xm = (m < 16) ? qpk[m] : lpk[m-16];
        a0 = __builtin_amdgcn_fdot2(u2h(xm), u2h(wv4.x), a0, false);
        a1 = __builtin_amdgcn_fdot2(u2h(xm), u2h(wv4.y), a1, false);
        a2 = __builtin_amdgcn_fdot2(u2h(xm), u2h(wv4.z), a2, false);
    }
    if (d < 32){
        G[l*96 + j] = a0; G[l*96 + SSN + j] = a1; G[l*96 + 2*SSN + j] = a2;
    }
}

// ---------------- readout: thread per (path, hop), f16 seq in ----------------
__global__ __launch_bounds__(256, 4) void k_readout(
    const unsigned* __restrict__ seq16, const int* __restrict__ l2p,
    const float* __restrict__ cap, const float* __restrict__ ft,
    const float* __restrict__ fpk,
    const float* __restrict__ w1, const float* __restrict__ b1,
    const float* __restrict__ w2, const float* __restrict__ b2,
    const float* __restrict__ w3, const float* __restrict__ b3,
    float* __restrict__ out)
{
    int g = blockIdx.x*256 + threadIdx.x;
    int p = g >> 3, t = g & 7;
    if (p >= PN) p = PN-1;               // tail: duplicate same-value writes, benign
    int lk = l2p[p*HN + t];
    const uint4* s4 = (const uint4*)(seq16 + (p*HN+t)*16);
    float sv[SSN];
    #pragma unroll
    for (int q=0;q<4;q++){
        uint4 v = s4[q];
        half2v a=u2h(v.x), b=u2h(v.y), c=u2h(v.z), e=u2h(v.w);
        sv[8*q+0]=(float)a.x; sv[8*q+1]=(float)a.y;
        sv[8*q+2]=(float)b.x; sv[8*q+3]=(float)b.y;
        sv[8*q+4]=(float)c.x; sv[8*q+5]=(float)c.y;
        sv[8*q+6]=(float)e.x; sv[8*q+7]=(float)e.y;
    }
    float h1[16];
    #pragma unroll
    for (int j=0;j<16;j++) h1[j] = b1[j];
    #pragma unroll
    for (int k=0;k<SSN;k++){
        float vk = sv[k];
        #pragma unroll
        for (int j=0;j<16;j++) h1[j] += vk*w1[k*16+j];
    }
    #pragma unroll
    for (int j=0;j<16;j++) h1[j] = fmaxf(h1[j], 0.f);
    float h2[16];
    #pragma unroll
    for (int j=0;j<16;j++) h2[j] = b2[j];
    #pragma unroll
    for (int k=0;k<16;k++){
        float hk = h1[k];
        #pragma unroll
        for (int j=0;j<16;j++) h2[j] += hk*w2[k*16+j];
    }
    float occ = b3[0];
    #pragma unroll
    for (int k=0;k<16;k++) occ += fmaxf(h2[k], 0.f)*w3[k];
    float icg = rcp_(cap[lk]) * 1e-9f;
    float qd  = occ * icg;
    float inv = icg;
    qd  += __shfl_xor(qd, 1);  inv += __shfl_xor(inv, 1);
    qd  += __shfl_xor(qd, 2);  inv += __shfl_xor(inv, 2);
    qd  += __shfl_xor(qd, 4);  inv += __shfl_xor(inv, 4);
    if ((threadIdx.x & 7) == 0)
        out[p] = qd + ft[p]*rcp_(fpk[p])*inv;
}

extern "C" void kernel_launch(void* const* d_in, const int* in_sizes, int n_in,
                              void* d_out, int out_size, void* d_ws, size_t ws_size,
                              hipStream_t stream)
{
    (void)in_sizes; (void)n_in; (void)out_size; (void)ws_size;
    const float* ft    = (const float*)d_in[0];
    const float* fpk   = (const float*)d_in[1];
    const float* flam  = (const float*)d_in[2];
    const float* fob   = (const float*)d_in[3];
    const float* fon   = (const float*)d_in[4];
    const float* foff  = (const float*)d_in[5];
    const float* cap   = (const float*)d_in[6];
    const float* pe_w1 = (const float*)d_in[7];
    const float* pe_b1 = (const float*)d_in[8];
    const float* pe_w2 = (const float*)d_in[9];
    const float* pe_b2 = (const float*)d_in[10];
    const float* le_w1 = (const float*)d_in[11];
    const float* le_b1 = (const float*)d_in[12];
    const float* le_w2 = (const float*)d_in[13];
    const float* le_b2 = (const float*)d_in[14];
    const float* qe_w1 = (const float*)d_in[15];
    const float* qe_b1 = (const float*)d_in[16];
    const float* qe_w2 = (const float*)d_in[17];
    const float* qe_b2 = (const float*)d_in[18];
    const float* pWx   = (const float*)d_in[19];
    const float* pWh   = (const float*)d_in[20];
    const float* pbi   = (const float*)d_in[21];
    const float* pbh   = (const float*)d_in[22];
    const float* qWx   = (const float*)d_in[23];
    const float* qWh   = (const float*)d_in[24];
    const float* qbi   = (const float*)d_in[25];
    const float* qbh   = (const float*)d_in[26];
    const float* lWx   = (const float*)d_in[27];
    const float* lWh   = (const float*)d_in[28];
    const float* lbi   = (const float*)d_in[29];
    const float* lbh   = (const float*)d_in[30];
    const float* ro_w1 = (const float*)d_in[31];
    const float* ro_b1 = (const float*)d_in[32];
    const float* ro_w2 = (const float*)d_in[33];
    const float* ro_b2 = (const float*)d_in[34];
    const float* ro_w3 = (const float*)d_in[35];
    const float* ro_b3 = (const float*)d_in[36];
    const int* fdist = (const int*)d_in[37];
    const int* btype = (const int*)d_in[38];
    const int* l2p   = (const int*)d_in[39];
    const int* p2l   = (const int*)d_in[40];
    const int* q2l   = (const int*)d_in[41];

    float* ws = (float*)d_ws;
    float* pWhp = ws + OFF_PWHP;
    float* path_state  = ws + OFF_PATH;
    unsigned* seq16    = (unsigned*)(ws + OFF_SEQ);
    unsigned* qwx16    = (unsigned*)(ws + OFF_QWX16);
    unsigned* qwh16    = (unsigned*)(ws + OFF_QWH16);
    unsigned* lwx16    = (unsigned*)(ws + OFF_LWX16);
    unsigned* lwh16    = (unsigned*)(ws + OFF_LWH16);
    unsigned* pwx16    = (unsigned*)(ws + OFF_PWX16);
    unsigned* qstate16 = (unsigned*)(ws + OFF_QST);
    unsigned* lstate16 = (unsigned*)(ws + OFF_LST);
    float* G           = ws + OFF_G;

    k_startup<<<2250, 256, 0, stream>>>(pWh, pWx, qWx, qWh, lWx, lWh, ws,
                                        ft, fpk, flam, fob, fon, foff, fdist,
                                        pe_w1, pe_b1, pe_w2, pe_b2, path_state,
                                        cap, p2l, btype,
                                        le_w1, le_b1, le_w2, le_b2,
                                        qe_w1, qe_b1, qe_w2, qe_b2,
                                        pbi, pbh, lstate16, qstate16, G);
    for (int it = 0; it < 7; ++it){
        k_path_gru<<<PN/4, 256, 0, stream>>>(G, l2p, pWhp, pbh, path_state, seq16);
        k_queue_gru<<<LN/2, 256, 0, stream>>>(seq16, p2l, qwx16, qwh16, qbi, qbh, qstate16);
        k_link_gru<<<LN/4, 256, 0, stream>>>(qstate16, q2l, lwx16, lwh16, lbi, lbh,
                                             pwx16, pbi, pbh, lstate16, G);
    }
    // 8th iteration: queue/link outputs are dead (readout uses only seq)
    k_path_gru<<<PN/4, 256, 0, stream>>>(G, l2p, pWhp, pbh, path_state, seq16);
    k_readout<<<(PN*HN+255)/256, 256, 0, stream>>>(seq16, l2p, cap, ft, fpk,
                                                   ro_w1, ro_b1, ro_w2, ro_b2, ro_w3, ro_b3,
                                                   (float*)d_out);
}

// Round 20
// 573.522 us; speedup vs baseline: 1.2493x; 1.1658x over previous
//
#include <hip/hip_runtime.h>
#include <hip/hip_fp16.h>

#define PN 50000
#define LN 8000
#define HN 8
#define DEGN 64
#define SSN 32

typedef _Float16 half2v __attribute__((ext_vector_type(2)));
typedef unsigned u2v __attribute__((ext_vector_type(2)));
static __device__ __forceinline__ half2v u2h(unsigned u){ half2v h; __builtin_memcpy(&h, &u, 4); return h; }
static __device__ __forceinline__ unsigned pkrtz(float a, float b){
    auto v = __builtin_amdgcn_cvt_pkrtz(a, b); unsigned u; __builtin_memcpy(&u, &v, 4); return u; }
static __device__ __forceinline__ float dpp_x1(float x){
    return __int_as_float(__builtin_amdgcn_update_dpp(0, __float_as_int(x), 0xB1, 0xF, 0xF, true)); }

// cross-half (lane j <-> lane j+32) sum via v_permlane32_swap (VALU, not DS)
static __device__ __forceinline__ float xhalf_sum(float v){
    u2v r = __builtin_amdgcn_permlane32_swap(__float_as_uint(v), __float_as_uint(v), false, false);
    return __uint_as_float(r.x) + __uint_as_float(r.y);
}

// ---- fast-but-accurate nonlinearities ----
static __device__ __forceinline__ float rcp_(float x){ return __builtin_amdgcn_rcpf(x); }
static __device__ __forceinline__ float sig_(float x){ return rcp_(1.0f + __expf(-x)); }
static __device__ __forceinline__ float tanh_(float x){ return 1.0f - 2.0f*rcp_(__expf(2.0f*x) + 1.0f); }

// ws layout (float offsets)
#define OFF_PWHP 0          // path_Wh f16 pairs [g(3)][q(4)][j(32)] uint4 = 1536 u32
#define OFF_PATH 27648      // path_state (P,32) f32                    1600000
#define OFF_SEQ  1627648    // seq (P,8,16) u32 f16-pairs               6400000
#define OFF_QWX16 14000000  // queue_Wx f16 pairs [m16][j][4] u32       2048
#define OFF_QWH16 14002048
#define OFF_LWX16 14004096
#define OFF_LWH16 14006144
#define OFF_PWX16 14008192  // path_Wx f16 pairs [m32][j][4] u32        4096
#define OFF_QST  14427648   // queue_state (L,16) u32 f16-pairs
#define OFF_LST  14683648   // link_state (L,16) u32 f16-pairs
#define OFF_G    14939648   // G (L,96) planes [{z,r,n}][j]; z,r include bi+bh

// ---------------- fused startup: pack + path_init + link_init ----------------
__global__ __launch_bounds__(256) void k_startup(
    const float* __restrict__ pWh, const float* __restrict__ pWx,
    const float* __restrict__ qWx, const float* __restrict__ qWh,
    const float* __restrict__ lWx, const float* __restrict__ lWh,
    float* __restrict__ ws,
    const float* __restrict__ ft, const float* __restrict__ fpk,
    const float* __restrict__ flam, const float* __restrict__ fob,
    const float* __restrict__ fon, const float* __restrict__ foff,
    const int* __restrict__ fdist,
    const float* __restrict__ pe_w1, const float* __restrict__ pe_b1,
    const float* __restrict__ pe_w2, const float* __restrict__ pe_b2,
    float* __restrict__ path_state,
    const float* __restrict__ cap,
    const int* __restrict__ p2l, const int* __restrict__ btype,
    const float* __restrict__ lw1, const float* __restrict__ lb1,
    const float* __restrict__ lw2, const float* __restrict__ lb2,
    const float* __restrict__ qw1, const float* __restrict__ qb1,
    const float* __restrict__ qw2, const float* __restrict__ qb2,
    const float* __restrict__ pbi, const float* __restrict__ pbh,
    unsigned* __restrict__ lstate16, unsigned* __restrict__ qstate16,
    float* __restrict__ G)
{
    __shared__ float tl[4][SSN], tq[4][SSN], x2[4][2*SSN];
    int b = blockIdx.x;
    if (b < 54){
        int i0 = b*256 + threadIdx.x;
        if (i0 < 1536){
            // [g(3)][q(4)][j(32)] uint4; c = word in quad; pair m = q*4+c
            int c = i0 & 3, slot = i0 >> 2;
            int j = slot & 31, gq = slot >> 5;
            int g = gq >> 2, q = gq & 2|(gq&3); q = gq & 3;
            int m = q*4 + c;
            float w0 = pWh[(2*m + 0)*96 + g*32 + j];
            float w1 = pWh[(2*m + 1)*96 + g*32 + j];
            ((unsigned*)(ws + OFF_PWHP))[i0] = pkrtz(w0, w1);
            return;
        }
        i0 -= 1536;
        if (i0 < 2048){ int m=i0>>7, rem=i0&127, j=rem>>2, g=rem&3;
            unsigned u=0; if (g<3) u = pkrtz(qWx[(2*m)*96+g*32+j], qWx[(2*m+1)*96+g*32+j]);
            ((unsigned*)(ws+OFF_QWX16))[i0]=u; return; }
        i0 -= 2048;
        if (i0 < 2048){ int m=i0>>7, rem=i0&127, j=rem>>2, g=rem&3;
            unsigned u=0; if (g<3) u = pkrtz(qWh[(2*m)*96+g*32+j], qWh[(2*m+1)*96+g*32+j]);
            ((unsigned*)(ws+OFF_QWH16))[i0]=u; return; }
        i0 -= 2048;
        if (i0 < 2048){ int m=i0>>7, rem=i0&127, j=rem>>2, g=rem&3;
            unsigned u=0; if (g<3) u = pkrtz(lWx[(2*m)*96+g*32+j], lWx[(2*m+1)*96+g*32+j]);
            ((unsigned*)(ws+OFF_LWX16))[i0]=u; return; }
        i0 -= 2048;
        if (i0 < 2048){ int m=i0>>7, rem=i0&127, j=rem>>2, g=rem&3;
            unsigned u=0; if (g<3) u = pkrtz(lWh[(2*m)*96+g*32+j], lWh[(2*m+1)*96+g*32+j]);
            ((unsigned*)(ws+OFF_LWH16))[i0]=u; return; }
        i0 -= 2048;
        if (i0 < 4096){ int m=i0>>7, rem=i0&127, j=rem>>2, g=rem&3;
            unsigned u=0; if (g<3) u = pkrtz(pWx[(2*m)*96+g*32+j], pWx[(2*m+1)*96+g*32+j]);
            ((unsigned*)(ws+OFF_PWX16))[i0]=u; return; }
        return;
    }
    if (b < 250){
        int p = (b-54)*256 + threadIdx.x; if (p >= PN) p = PN-1;
        float f[9];
        f[0]=ft[p]; f[1]=fpk[p];
        int dcls = fdist[p];
        f[2] = (dcls==0)?1.f:0.f; f[3]=(dcls==1)?1.f:0.f; f[4]=(dcls==2)?1.f:0.f;
        f[5]=flam[p]; f[6]=fob[p]; f[7]=fon[p]; f[8]=foff[p];
        float h1[SSN];
        #pragma unroll
        for (int j=0;j<SSN;j++){
            float a = pe_b1[j];
            #pragma unroll
            for (int k=0;k<9;k++) a += f[k]*pe_w1[k*SSN+j];
            h1[j] = fmaxf(a, 0.f);
        }
        #pragma unroll
        for (int j=0;j<SSN;j++){
            float a = pe_b2[j];
            #pragma unroll
            for (int k=0;k<SSN;k++) a += h1[k]*pe_w2[k*SSN+j];
            path_state[p*SSN+j] = fmaxf(a, 0.f);
        }
        return;
    }
    {
        int wid = threadIdx.x >> 6, d = threadIdx.x & 63, j = d & 31;
        int l = (b-250)*4 + wid;         // 2000*4 == 8000 exactly
        float s = ft[p2l[(l*DEGN+d)*2]];
        s += __shfl_xor(s, 1);  s += __shfl_xor(s, 2);  s += __shfl_xor(s, 4);
        s += __shfl_xor(s, 8);  s += __shfl_xor(s, 16); s += __shfl_xor(s, 32);
        float load = s / cap[l];
        int bt = btype[l];
        if (d < 32){
            tl[wid][j] = fmaxf(load*lw1[j] + lb1[j], 0.f);
            tq[wid][j] = fmaxf(qw1[bt*SSN+j] + qb1[j], 0.f);
        }
        __syncthreads();
        float al = lb2[j], aq = qb2[j];
        #pragma unroll
        for (int k=0;k<SSN;k++){
            al += tl[wid][k]*lw2[k*SSN+j];
            aq += tq[wid][k]*qw2[k*SSN+j];
        }
        float ls = fmaxf(al, 0.f), qs = fmaxf(aq, 0.f);
        float ls_o = dpp_x1(ls), qs_o = dpp_x1(qs);
        if (d < 32){
            if (!(d & 1)){
                lstate16[l*16 + (j>>1)] = pkrtz(ls, ls_o);
                qstate16[l*16 + (j>>1)] = pkrtz(qs, qs_o);
            }
            x2[wid][j] = qs; x2[wid][SSN+j] = ls;
        }
        __syncthreads();
        float a0=pbi[j]+pbh[j], a1=pbi[SSN+j]+pbh[SSN+j], a2=pbi[2*SSN+j];
        #pragma unroll
        for (int k=0;k<2*SSN;k++){
            float xk = x2[wid][k];
            a0 += xk*pWx[k*96 + j];
            a1 += xk*pWx[k*96 + SSN + j];
            a2 += xk*pWx[k*96 + 2*SSN + j];
        }
        if (d < 32){
            G[l*96 + j] = a0; G[l*96 + SSN + j] = a1; G[l*96 + 2*SSN + j] = a2;
        }
    }
}

// ---------------- path GRU scan: 2 paths/wave, full-k, LDS weights -----------
// Each 32-lane half owns one path; lane = (path-half, j). Full k=32 per lane
// (16 pair-fdot2 per gate) -> NO cross-lane reduce, no duplicated gate work.
// Weights staged once per block in LDS (6 KB, remat-proof), read as 12
// conflict-free ds_read_b128/hop (2-way same-address broadcast across halves).
__global__ __launch_bounds__(256)
void k_path_gru(
    const float* __restrict__ G, const int* __restrict__ l2p,
    const unsigned* __restrict__ Whp, const float* __restrict__ bh,
    float* __restrict__ path_state, unsigned* __restrict__ seq16)
{
    __shared__ uint4 wlds[384];               // [g(3)][q(4)][j(32)]
    __shared__ unsigned hsh[4][32];           // per wave: 16 pair-words x 2 paths
    const int tid   = threadIdx.x;
    const int lane  = tid & 63;
    const int j     = lane & 31;
    const int half  = lane >> 5;
    const int wslot = tid >> 6;
    const bool wr   = !(lane & 1);
    const int p = blockIdx.x*8 + (wslot<<1) + half;   // 6250*8 == 50000
    #pragma unroll
    for (int i = tid; i < 384; i += 256) wlds[i] = ((const uint4*)Whp)[i];
    __syncthreads();
    const float bn = bh[2*SSN + j];
    const int4 la = *(const int4*)(l2p + p*HN);
    const int4 lb = *(const int4*)(l2p + p*HN + 4);
    float hj = path_state[p*SSN + j];
    {   // publish initial h pairs (own half's 16 words)
        float oth = dpp_x1(hj);
        if (wr) hsh[wslot][half*16 + (j>>1)] = pkrtz(hj, oth);
    }
    float cz, cr, cn, nz, nr, nn;
    { const float* g = G + la.x*96; cz=g[j]; cr=g[SSN+j]; cn=g[2*SSN+j]; }

#define GDOT(acc_, gbase_, hv_, qi_) { \
    uint4 wv = wlds[(gbase_ + qi_)*32 + j]; \
    acc_ = __builtin_amdgcn_fdot2(u2h(hv_.x), u2h(wv.x), acc_, false); \
    acc_ = __builtin_amdgcn_fdot2(u2h(hv_.y), u2h(wv.y), acc_, false); \
    acc_ = __builtin_amdgcn_fdot2(u2h(hv_.z), u2h(wv.z), acc_, false); \
    acc_ = __builtin_amdgcn_fdot2(u2h(hv_.w), u2h(wv.w), acc_, false); }
#define PF(L_) { const float* g = G + (L_)*96; nz=g[j]; nr=g[SSN+j]; nn=g[2*SSN+j]; }
#define HOP(T_) { \
    asm volatile("" ::: "memory"); \
    const uint4* hp = (const uint4*)&hsh[wslot][half*16]; \
    uint4 h0 = hp[0], h1 = hp[1], h2 = hp[2], h3 = hp[3]; \
    float az=0.f, ar=0.f, an=0.f; \
    GDOT(az, 0, h0, 0) GDOT(az, 0, h1, 1) GDOT(az, 0, h2, 2) GDOT(az, 0, h3, 3) \
    GDOT(ar, 4, h0, 0) GDOT(ar, 4, h1, 1) GDOT(ar, 4, h2, 2) GDOT(ar, 4, h3, 3) \
    GDOT(an, 8, h0, 0) GDOT(an, 8, h1, 1) GDOT(an, 8, h2, 2) GDOT(an, 8, h3, 3) \
    float z = sig_(cz + az); \
    float r = sig_(cr + ar); \
    float n = tanh_(cn + r*(an + bn)); \
    hj = z*hj + (1.0f-z)*n; \
    float oth = dpp_x1(hj); \
    unsigned pk = pkrtz(hj, oth); \
    if (wr){ hsh[wslot][half*16 + (j>>1)] = pk; seq16[(p*HN+T_)*16 + (j>>1)] = pk; } \
    cz = nz; cr = nr; cn = nn; }

    PF(la.y) HOP(0)
    PF(la.z) HOP(1)
    PF(la.w) HOP(2)
    PF(lb.x) HOP(3)
    PF(lb.y) HOP(4)
    PF(lb.z) HOP(5)
    PF(lb.w) HOP(6)
    HOP(7)
#undef PF
#undef HOP
#undef GDOT
    path_state[p*SSN + j] = hj;
}

// ---------------- queue GRU: 2-wave gather + f16 dot2, f16 state -------------
__global__ __launch_bounds__(256) void k_queue_gru(
    const unsigned* __restrict__ seq16, const int* __restrict__ p2l,
    const unsigned* __restrict__ wx16, const unsigned* __restrict__ wh16,
    const float* __restrict__ bi, const float* __restrict__ bhb,
    unsigned* __restrict__ qstate16)
{
    __shared__ float red[2][DEGN][SSN+1];
    __shared__ unsigned xpk_lds[2][16];
    int tid  = threadIdx.x;
    int wv   = tid >> 6;
    int slot = wv >> 1;
    int wp   = wv & 1;
    int lane = tid & 63;
    int r    = (lane & 31) + (wp << 5);
    int half = lane >> 5;
    int l = __builtin_amdgcn_readfirstlane(blockIdx.x*2 + slot);   // 4000*2 == 8000
    int pp  = p2l[(l*DEGN + r)*2 + 0];
    int pos = p2l[(l*DEGN + r)*2 + 1];
    const uint4* row = (const uint4*)(seq16 + (pp*HN + pos - 1)*16 + half*8);
    uint4 v0 = row[0], v1 = row[1];
    float* dst = &red[slot][r][16*half];
    {
        half2v a,b;
        a=u2h(v0.x); b=u2h(v0.y); dst[ 0]=(float)a.x; dst[ 1]=(float)a.y; dst[ 2]=(float)b.x; dst[ 3]=(float)b.y;
        a=u2h(v0.z); b=u2h(v0.w); dst[ 4]=(float)a.x; dst[ 5]=(float)a.y; dst[ 6]=(float)b.x; dst[ 7]=(float)b.y;
        a=u2h(v1.x); b=u2h(v1.y); dst[ 8]=(float)a.x; dst[ 9]=(float)a.y; dst[10]=(float)b.x; dst[11]=(float)b.y;
        a=u2h(v1.z); b=u2h(v1.w); dst[12]=(float)a.x; dst[13]=(float)a.y; dst[14]=(float)b.x; dst[15]=(float)b.y;
    }
    __syncthreads();
    if (wp) return;                          // gather-only wave retires
    int j = lane & 31;
    int base = (lane < 32) ? 0 : 32;
    float xs = 0.f;
    #pragma unroll
    for (int dd=0; dd<32; dd++) xs += red[slot][base+dd][j];
    xs = xhalf_sum(xs);
    {
        float oth = dpp_x1(xs);
        unsigned pkx = pkrtz(xs, oth);
        if (lane < 32 && !(lane & 1)) xpk_lds[slot][j>>1] = pkx;
    }
    unsigned hpk[16];
    {
        const uint4* h4 = (const uint4*)(qstate16 + l*16);
        #pragma unroll
        for (int q=0;q<4;q++){ uint4 v=h4[q]; hpk[4*q]=v.x; hpk[4*q+1]=v.y; hpk[4*q+2]=v.z; hpk[4*q+3]=v.w; }
    }
    half2v hw = u2h(hpk[j>>1]);
    float hj = (j & 1) ? (float)hw.y : (float)hw.x;
    unsigned xq[16];
    {
        asm volatile("" ::: "memory");
        const uint4* xl = (const uint4*)xpk_lds[slot];
        #pragma unroll
        for (int q=0;q<4;q++){ uint4 v=xl[q]; xq[4*q]=v.x; xq[4*q+1]=v.y; xq[4*q+2]=v.z; xq[4*q+3]=v.w; }
    }
    float az = bi[j] + bhb[j];
    float ar = bi[SSN+j] + bhb[SSN+j];
    float xn = bi[2*SSN+j];
    float hn = bhb[2*SSN+j];
    #pragma unroll
    for (int m=0;m<16;m++){
        uint4 wx4 = ((const uint4*)wx16)[m*32 + j];
        uint4 wh4 = ((const uint4*)wh16)[m*32 + j];
        az = __builtin_amdgcn_fdot2(u2h(xq[m]),  u2h(wx4.x), az, false);
        ar = __builtin_amdgcn_fdot2(u2h(xq[m]),  u2h(wx4.y), ar, false);
        xn = __builtin_amdgcn_fdot2(u2h(xq[m]),  u2h(wx4.z), xn, false);
        az = __builtin_amdgcn_fdot2(u2h(hpk[m]), u2h(wh4.x), az, false);
        ar = __builtin_amdgcn_fdot2(u2h(hpk[m]), u2h(wh4.y), ar, false);
        hn = __builtin_amdgcn_fdot2(u2h(hpk[m]), u2h(wh4.z), hn, false);
    }
    float z = sig_(az), r2 = sig_(ar);
    float n = tanh_(xn + r2*hn);
    float outv = z*hj + (1.0f-z)*n;
    float oth = dpp_x1(outv);
    if (lane < 32 && !(lane & 1))
        qstate16[l*16 + (j>>1)] = pkrtz(outv, oth);
}

// ---------------- link GRU + next-iteration G: f16 state, scalar rows --------
__global__ __launch_bounds__(256) void k_link_gru(
    const unsigned* __restrict__ qstate16, const int* __restrict__ q2l,
    const unsigned* __restrict__ wx16, const unsigned* __restrict__ wh16,
    const float* __restrict__ bi, const float* __restrict__ bhb,
    const unsigned* __restrict__ pwx16, const float* __restrict__ pbi,
    const float* __restrict__ pbh,
    unsigned* __restrict__ lstate16, float* __restrict__ G)
{
    __shared__ unsigned lpk_lds[4][16];
    int wid = threadIdx.x >> 6, d = threadIdx.x & 63, j = d & 31;
    int l = __builtin_amdgcn_readfirstlane(blockIdx.x*4 + wid);
    int src = __builtin_amdgcn_readfirstlane(q2l[l]);
    unsigned xpk[16], hpk[16], qpk[16];
    {
        const uint4* x4 = (const uint4*)(qstate16 + src*16);
        const uint4* h4 = (const uint4*)(lstate16 + l*16);
        const uint4* q4 = (const uint4*)(qstate16 + l*16);
        #pragma unroll
        for (int q=0;q<4;q++){
            uint4 a=x4[q]; xpk[4*q]=a.x; xpk[4*q+1]=a.y; xpk[4*q+2]=a.z; xpk[4*q+3]=a.w;
            uint4 b=h4[q]; hpk[4*q]=b.x; hpk[4*q+1]=b.y; hpk[4*q+2]=b.z; hpk[4*q+3]=b.w;
            uint4 c=q4[q]; qpk[4*q]=c.x; qpk[4*q+1]=c.y; qpk[4*q+2]=c.z; qpk[4*q+3]=c.w;
        }
    }
    half2v hw = u2h(hpk[j>>1]);
    float hj = (j & 1) ? (float)hw.y : (float)hw.x;
    float az = bi[j]+bhb[j], ar = bi[SSN+j]+bhb[SSN+j];
    float xn = bi[2*SSN+j], hn = bhb[2*SSN+j];
    #pragma unroll
    for (int m=0;m<16;m++){
        uint4 wx4 = ((const uint4*)wx16)[m*32 + j];
        uint4 wh4 = ((const uint4*)wh16)[m*32 + j];
        az = __builtin_amdgcn_fdot2(u2h(xpk[m]), u2h(wx4.x), az, false);
        ar = __builtin_amdgcn_fdot2(u2h(xpk[m]), u2h(wx4.y), ar, false);
        xn = __builtin_amdgcn_fdot2(u2h(xpk[m]), u2h(wx4.z), xn, false);
        az = __builtin_amdgcn_fdot2(u2h(hpk[m]), u2h(wh4.x), az, false);
        ar = __builtin_amdgcn_fdot2(u2h(hpk[m]), u2h(wh4.y), ar, false);
        hn = __builtin_amdgcn_fdot2(u2h(hpk[m]), u2h(wh4.z), hn, false);
    }
    float z = sig_(az), r = sig_(ar);
    float n = tanh_(xn + r*hn);
    float outv = z*hj + (1.0f-z)*n;
    {
        float oth = dpp_x1(outv);
        unsigned pko = pkrtz(outv, oth);
        if (d < 32 && !(d & 1)){ lstate16[l*16 + (j>>1)] = pko; lpk_lds[wid][j>>1] = pko; }
    }
    unsigned lpk[16];
    {
        asm volatile("" ::: "memory");
        const uint4* ll = (const uint4*)lpk_lds[wid];
        #pragma unroll
        for (int q=0;q<4;q++){ uint4 v=ll[q]; lpk[4*q]=v.x; lpk[4*q+1]=v.y; lpk[4*q+2]=v.z; lpk[4*q+3]=v.w; }
    }
    float a0 = pbi[j]+pbh[j], a1 = pbi[SSN+j]+pbh[SSN+j], a2 = pbi[2*SSN+j];
    #pragma unroll
    for (int m=0;m<32;m++){
        uint4 wv4 = ((const uint4*)pwx16)[m*32 + j];
        unsigned xm = (m < 16) ? qpk[m] : lpk[m-16];
        a0 = __builtin_amdgcn_fdot2(u2h(xm), u2h(wv4.x), a0, false);
        a1 = __builtin_amdgcn_fdot2(u2h(xm), u2h(wv4.y), a1, false);
        a2 = __builtin_amdgcn_fdot2(u2h(xm), u2h(wv4.z), a2, false);
    }
    if (d < 32){
        G[l*96 + j] = a0; G[l*96 + SSN + j] = a1; G[l*96 + 2*SSN + j] = a2;
    }
}

// ---------------- readout: thread per (path, hop), f16 seq in ----------------
__global__ __launch_bounds__(256, 4) void k_readout(
    const unsigned* __restrict__ seq16, const int* __restrict__ l2p,
    const float* __restrict__ cap, const float* __restrict__ ft,
    const float* __restrict__ fpk,
    const float* __restrict__ w1, const float* __restrict__ b1,
    const float* __restrict__ w2, const float* __restrict__ b2,
    const float* __restrict__ w3, const float* __restrict__ b3,
    float* __restrict__ out)
{
    int g = blockIdx.x*256 + threadIdx.x;
    int p = g >> 3, t = g & 7;
    if (p >= PN) p = PN-1;               // tail: duplicate same-value writes, benign
    int lk = l2p[p*HN + t];
    const uint4* s4 = (const uint4*)(seq16 + (p*HN+t)*16);
    float sv[SSN];
    #pragma unroll
    for (int q=0;q<4;q++){
        uint4 v = s4[q];
        half2v a=u2h(v.x), b=u2h(v.y), c=u2h(v.z), e=u2h(v.w);
        sv[8*q+0]=(float)a.x; sv[8*q+1]=(float)a.y;
        sv[8*q+2]=(float)b.x; sv[8*q+3]=(float)b.y;
        sv[8*q+4]=(float)c.x; sv[8*q+5]=(float)c.y;
        sv[8*q+6]=(float)e.x; sv[8*q+7]=(float)e.y;
    }
    float h1[16];
    #pragma unroll
    for (int j=0;j<16;j++) h1[j] = b1[j];
    #pragma unroll
    for (int k=0;k<SSN;k++){
        float vk = sv[k];
        #pragma unroll
        for (int j=0;j<16;j++) h1[j] += vk*w1[k*16+j];
    }
    #pragma unroll
    for (int j=0;j<16;j++) h1[j] = fmaxf(h1[j], 0.f);
    float h2[16];
    #pragma unroll
    for (int j=0;j<16;j++) h2[j] = b2[j];
    #pragma unroll
    for (int k=0;k<16;k++){
        float hk = h1[k];
        #pragma unroll
        for (int j=0;j<16;j++) h2[j] += hk*w2[k*16+j];
    }
    float occ = b3[0];
    #pragma unroll
    for (int k=0;k<16;k++) occ += fmaxf(h2[k], 0.f)*w3[k];
    float icg = rcp_(cap[lk]) * 1e-9f;
    float qd  = occ * icg;
    float inv = icg;
    qd  += __shfl_xor(qd, 1);  inv += __shfl_xor(inv, 1);
    qd  += __shfl_xor(qd, 2);  inv += __shfl_xor(inv, 2);
    qd  += __shfl_xor(qd, 4);  inv += __shfl_xor(inv, 4);
    if ((threadIdx.x & 7) == 0)
        out[p] = qd + ft[p]*rcp_(fpk[p])*inv;
}

extern "C" void kernel_launch(void* const* d_in, const int* in_sizes, int n_in,
                              void* d_out, int out_size, void* d_ws, size_t ws_size,
                              hipStream_t stream)
{
    (void)in_sizes; (void)n_in; (void)out_size; (void)ws_size;
    const float* ft    = (const float*)d_in[0];
    const float* fpk   = (const float*)d_in[1];
    const float* flam  = (const float*)d_in[2];
    const float* fob   = (const float*)d_in[3];
    const float* fon   = (const float*)d_in[4];
    const float* foff  = (const float*)d_in[5];
    const float* cap   = (const float*)d_in[6];
    const float* pe_w1 = (const float*)d_in[7];
    const float* pe_b1 = (const float*)d_in[8];
    const float* pe_w2 = (const float*)d_in[9];
    const float* pe_b2 = (const float*)d_in[10];
    const float* le_w1 = (const float*)d_in[11];
    const float* le_b1 = (const float*)d_in[12];
    const float* le_w2 = (const float*)d_in[13];
    const float* le_b2 = (const float*)d_in[14];
    const float* qe_w1 = (const float*)d_in[15];
    const float* qe_b1 = (const float*)d_in[16];
    const float* qe_w2 = (const float*)d_in[17];
    const float* qe_b2 = (const float*)d_in[18];
    const float* pWx   = (const float*)d_in[19];
    const float* pWh   = (const float*)d_in[20];
    const float* pbi   = (const float*)d_in[21];
    const float* pbh   = (const float*)d_in[22];
    const float* qWx   = (const float*)d_in[23];
    const float* qWh   = (const float*)d_in[24];
    const float* qbi   = (const float*)d_in[25];
    const float* qbh   = (const float*)d_in[26];
    const float* lWx   = (const float*)d_in[27];
    const float* lWh   = (const float*)d_in[28];
    const float* lbi   = (const float*)d_in[29];
    const float* lbh   = (const float*)d_in[30];
    const float* ro_w1 = (const float*)d_in[31];
    const float* ro_b1 = (const float*)d_in[32];
    const float* ro_w2 = (const float*)d_in[33];
    const float* ro_b2 = (const float*)d_in[34];
    const float* ro_w3 = (const float*)d_in[35];
    const float* ro_b3 = (const float*)d_in[36];
    const int* fdist = (const int*)d_in[37];
    const int* btype = (const int*)d_in[38];
    const int* l2p   = (const int*)d_in[39];
    const int* p2l   = (const int*)d_in[40];
    const int* q2l   = (const int*)d_in[41];

    float* ws = (float*)d_ws;
    unsigned* pWhp16   = (unsigned*)(ws + OFF_PWHP);
    float* path_state  = ws + OFF_PATH;
    unsigned* seq16    = (unsigned*)(ws + OFF_SEQ);
    unsigned* qwx16    = (unsigned*)(ws + OFF_QWX16);
    unsigned* qwh16    = (unsigned*)(ws + OFF_QWH16);
    unsigned* lwx16    = (unsigned*)(ws + OFF_LWX16);
    unsigned* lwh16    = (unsigned*)(ws + OFF_LWH16);
    unsigned* pwx16    = (unsigned*)(ws + OFF_PWX16);
    unsigned* qstate16 = (unsigned*)(ws + OFF_QST);
    unsigned* lstate16 = (unsigned*)(ws + OFF_LST);
    float* G           = ws + OFF_G;

    k_startup<<<2250, 256, 0, stream>>>(pWh, pWx, qWx, qWh, lWx, lWh, ws,
                                        ft, fpk, flam, fob, fon, foff, fdist,
                                        pe_w1, pe_b1, pe_w2, pe_b2, path_state,
                                        cap, p2l, btype,
                                        le_w1, le_b1, le_w2, le_b2,
                                        qe_w1, qe_b1, qe_w2, qe_b2,
                                        pbi, pbh, lstate16, qstate16, G);
    for (int it = 0; it < 7; ++it){
        k_path_gru<<<PN/8, 256, 0, stream>>>(G, l2p, pWhp16, pbh, path_state, seq16);
        k_queue_gru<<<LN/2, 256, 0, stream>>>(seq16, p2l, qwx16, qwh16, qbi, qbh, qstate16);
        k_link_gru<<<LN/4, 256, 0, stream>>>(qstate16, q2l, lwx16, lwh16, lbi, lbh,
                                             pwx16, pbi, pbh, lstate16, G);
    }
    // 8th iteration: queue/link outputs are dead (readout uses only seq)
    k_path_gru<<<PN/8, 256, 0, stream>>>(G, l2p, pWhp16, pbh, path_state, seq16);
    k_readout<<<(PN*HN+255)/256, 256, 0, stream>>>(seq16, l2p, cap, ft, fpk,
                                                   ro_w1, ro_b1, ro_w2, ro_b2, ro_w3, ro_b3,
                                                   (float*)d_out);
}

// Round 21
// 573.209 us; speedup vs baseline: 1.2500x; 1.0005x over previous
//
#include <hip/hip_runtime.h>
#include <hip/hip_fp16.h>

#define PN 50000
#define LN 8000
#define HN 8
#define DEGN 64
#define SSN 32

typedef _Float16 half2v __attribute__((ext_vector_type(2)));
typedef unsigned u2v __attribute__((ext_vector_type(2)));
static __device__ __forceinline__ half2v u2h(unsigned u){ half2v h; __builtin_memcpy(&h, &u, 4); return h; }
static __device__ __forceinline__ unsigned pkrtz(float a, float b){
    auto v = __builtin_amdgcn_cvt_pkrtz(a, b); unsigned u; __builtin_memcpy(&u, &v, 4); return u; }
static __device__ __forceinline__ float dpp_x1(float x){
    return __int_as_float(__builtin_amdgcn_update_dpp(0, __float_as_int(x), 0xB1, 0xF, 0xF, true)); }

// cross-half (lane j <-> lane j+32) sum via v_permlane32_swap (VALU, not DS)
static __device__ __forceinline__ float xhalf_sum(float v){
    u2v r = __builtin_amdgcn_permlane32_swap(__float_as_uint(v), __float_as_uint(v), false, false);
    return __uint_as_float(r.x) + __uint_as_float(r.y);
}

// ---- fast-but-accurate nonlinearities ----
static __device__ __forceinline__ float rcp_(float x){ return __builtin_amdgcn_rcpf(x); }
static __device__ __forceinline__ float sig_(float x){ return rcp_(1.0f + __expf(-x)); }
static __device__ __forceinline__ float tanh_(float x){ return 1.0f - 2.0f*rcp_(__expf(2.0f*x) + 1.0f); }

// ws layout (float offsets)
#define OFF_PWHP 0          // path_Wh f16 pairs [g(3)][q(4)][j(32)] uint4 = 1536 u32
#define OFF_PATH 27648      // path_state (P,32) f32                    1600000
#define OFF_SEQ  1627648    // seq (P,8,16) u32 f16-pairs               6400000
#define OFF_QWX16 14000000  // queue_Wx f16 pairs [m16][j][4] u32       2048
#define OFF_QWH16 14002048
#define OFF_LWX16 14004096
#define OFF_LWH16 14006144
#define OFF_PWX16 14008192  // path_Wx f16 pairs [m32][j][4] u32        4096
#define OFF_QST  14427648   // queue_state (L,16) u32 f16-pairs
#define OFF_LST  14683648   // link_state (L,16) u32 f16-pairs
#define OFF_G    14939648   // G16 (L,48) u32: [zr pair per col j (32)] [n pairs (16)]

// ---------------- fused startup: pack + path_init + link_init ----------------
__global__ __launch_bounds__(256) void k_startup(
    const float* __restrict__ pWh, const float* __restrict__ pWx,
    const float* __restrict__ qWx, const float* __restrict__ qWh,
    const float* __restrict__ lWx, const float* __restrict__ lWh,
    float* __restrict__ ws,
    const float* __restrict__ ft, const float* __restrict__ fpk,
    const float* __restrict__ flam, const float* __restrict__ fob,
    const float* __restrict__ fon, const float* __restrict__ foff,
    const int* __restrict__ fdist,
    const float* __restrict__ pe_w1, const float* __restrict__ pe_b1,
    const float* __restrict__ pe_w2, const float* __restrict__ pe_b2,
    float* __restrict__ path_state,
    const float* __restrict__ cap,
    const int* __restrict__ p2l, const int* __restrict__ btype,
    const float* __restrict__ lw1, const float* __restrict__ lb1,
    const float* __restrict__ lw2, const float* __restrict__ lb2,
    const float* __restrict__ qw1, const float* __restrict__ qb1,
    const float* __restrict__ qw2, const float* __restrict__ qb2,
    const float* __restrict__ pbi, const float* __restrict__ pbh,
    unsigned* __restrict__ lstate16, unsigned* __restrict__ qstate16,
    unsigned* __restrict__ G16)
{
    __shared__ float tl[4][SSN], tq[4][SSN], x2[4][2*SSN];
    int b = blockIdx.x;
    if (b < 54){
        int i0 = b*256 + threadIdx.x;
        if (i0 < 1536){
            // [g(3)][q(4)][j(32)] uint4; c = word in quad; pair m = q*4+c
            int c = i0 & 3, slot = i0 >> 2;
            int j = slot & 31, gq = slot >> 5;
            int g = gq >> 2, q = gq & 3;
            int m = q*4 + c;
            float w0 = pWh[(2*m + 0)*96 + g*32 + j];
            float w1 = pWh[(2*m + 1)*96 + g*32 + j];
            ((unsigned*)(ws + OFF_PWHP))[i0] = pkrtz(w0, w1);
            return;
        }
        i0 -= 1536;
        if (i0 < 2048){ int m=i0>>7, rem=i0&127, j=rem>>2, g=rem&3;
            unsigned u=0; if (g<3) u = pkrtz(qWx[(2*m)*96+g*32+j], qWx[(2*m+1)*96+g*32+j]);
            ((unsigned*)(ws+OFF_QWX16))[i0]=u; return; }
        i0 -= 2048;
        if (i0 < 2048){ int m=i0>>7, rem=i0&127, j=rem>>2, g=rem&3;
            unsigned u=0; if (g<3) u = pkrtz(qWh[(2*m)*96+g*32+j], qWh[(2*m+1)*96+g*32+j]);
            ((unsigned*)(ws+OFF_QWH16))[i0]=u; return; }
        i0 -= 2048;
        if (i0 < 2048){ int m=i0>>7, rem=i0&127, j=rem>>2, g=rem&3;
            unsigned u=0; if (g<3) u = pkrtz(lWx[(2*m)*96+g*32+j], lWx[(2*m+1)*96+g*32+j]);
            ((unsigned*)(ws+OFF_LWX16))[i0]=u; return; }
        i0 -= 2048;
        if (i0 < 2048){ int m=i0>>7, rem=i0&127, j=rem>>2, g=rem&3;
            unsigned u=0; if (g<3) u = pkrtz(lWh[(2*m)*96+g*32+j], lWh[(2*m+1)*96+g*32+j]);
            ((unsigned*)(ws+OFF_LWH16))[i0]=u; return; }
        i0 -= 2048;
        if (i0 < 4096){ int m=i0>>7, rem=i0&127, j=rem>>2, g=rem&3;
            unsigned u=0; if (g<3) u = pkrtz(pWx[(2*m)*96+g*32+j], pWx[(2*m+1)*96+g*32+j]);
            ((unsigned*)(ws+OFF_PWX16))[i0]=u; return; }
        return;
    }
    if (b < 250){
        int p = (b-54)*256 + threadIdx.x; if (p >= PN) p = PN-1;
        float f[9];
        f[0]=ft[p]; f[1]=fpk[p];
        int dcls = fdist[p];
        f[2] = (dcls==0)?1.f:0.f; f[3]=(dcls==1)?1.f:0.f; f[4]=(dcls==2)?1.f:0.f;
        f[5]=flam[p]; f[6]=fob[p]; f[7]=fon[p]; f[8]=foff[p];
        float h1[SSN];
        #pragma unroll
        for (int j=0;j<SSN;j++){
            float a = pe_b1[j];
            #pragma unroll
            for (int k=0;k<9;k++) a += f[k]*pe_w1[k*SSN+j];
            h1[j] = fmaxf(a, 0.f);
        }
        #pragma unroll
        for (int j=0;j<SSN;j++){
            float a = pe_b2[j];
            #pragma unroll
            for (int k=0;k<SSN;k++) a += h1[k]*pe_w2[k*SSN+j];
            path_state[p*SSN+j] = fmaxf(a, 0.f);
        }
        return;
    }
    {
        int wid = threadIdx.x >> 6, d = threadIdx.x & 63, j = d & 31;
        int l = (b-250)*4 + wid;         // 2000*4 == 8000 exactly
        float s = ft[p2l[(l*DEGN+d)*2]];
        s += __shfl_xor(s, 1);  s += __shfl_xor(s, 2);  s += __shfl_xor(s, 4);
        s += __shfl_xor(s, 8);  s += __shfl_xor(s, 16); s += __shfl_xor(s, 32);
        float load = s / cap[l];
        int bt = btype[l];
        if (d < 32){
            tl[wid][j] = fmaxf(load*lw1[j] + lb1[j], 0.f);
            tq[wid][j] = fmaxf(qw1[bt*SSN+j] + qb1[j], 0.f);
        }
        __syncthreads();
        float al = lb2[j], aq = qb2[j];
        #pragma unroll
        for (int k=0;k<SSN;k++){
            al += tl[wid][k]*lw2[k*SSN+j];
            aq += tq[wid][k]*qw2[k*SSN+j];
        }
        float ls = fmaxf(al, 0.f), qs = fmaxf(aq, 0.f);
        float ls_o = dpp_x1(ls), qs_o = dpp_x1(qs);
        if (d < 32){
            if (!(d & 1)){
                lstate16[l*16 + (j>>1)] = pkrtz(ls, ls_o);
                qstate16[l*16 + (j>>1)] = pkrtz(qs, qs_o);
            }
            x2[wid][j] = qs; x2[wid][SSN+j] = ls;
        }
        __syncthreads();
        float a0=pbi[j]+pbh[j], a1=pbi[SSN+j]+pbh[SSN+j], a2=pbi[2*SSN+j];
        #pragma unroll
        for (int k=0;k<2*SSN;k++){
            float xk = x2[wid][k];
            a0 += xk*pWx[k*96 + j];
            a1 += xk*pWx[k*96 + SSN + j];
            a2 += xk*pWx[k*96 + 2*SSN + j];
        }
        if (d < 32){
            G16[l*48 + j] = pkrtz(a0, a1);          // z,r packed per col
            float a2o = dpp_x1(a2);
            if (!(d & 1)) G16[l*48 + 32 + (j>>1)] = pkrtz(a2, a2o);  // n pairs
        }
    }
}

// ---------------- path GRU scan: 2 paths/wave, full-k, LDS weights, f16 G ----
__global__ __launch_bounds__(256)
void k_path_gru(
    const unsigned* __restrict__ G16, const int* __restrict__ l2p,
    const unsigned* __restrict__ Whp, const float* __restrict__ bh,
    float* __restrict__ path_state, unsigned* __restrict__ seq16)
{
    __shared__ uint4 wlds[384];               // [g(3)][q(4)][j(32)]
    __shared__ unsigned hsh[4][32];           // per wave: 16 pair-words x 2 paths
    const int tid   = threadIdx.x;
    const int lane  = tid & 63;
    const int j     = lane & 31;
    const int half  = lane >> 5;
    const int wslot = tid >> 6;
    const bool wr   = !(lane & 1);
    const int p = blockIdx.x*8 + (wslot<<1) + half;   // 6250*8 == 50000
    #pragma unroll
    for (int i = tid; i < 384; i += 256) wlds[i] = ((const uint4*)Whp)[i];
    __syncthreads();
    const float bn = bh[2*SSN + j];
    const int4 la = *(const int4*)(l2p + p*HN);
    const int4 lb = *(const int4*)(l2p + p*HN + 4);
    float hj = path_state[p*SSN + j];
    {   // publish initial h pairs (own half's 16 words)
        float oth = dpp_x1(hj);
        if (wr) hsh[wslot][half*16 + (j>>1)] = pkrtz(hj, oth);
    }
    float cz, cr, cn, nz, nr, nn;
    {
        const unsigned* g16 = G16 + la.x*48;
        half2v zr = u2h(g16[j]); cz=(float)zr.x; cr=(float)zr.y;
        half2v nw = u2h(g16[32+(j>>1)]); cn = (j&1)? (float)nw.y : (float)nw.x;
    }

#define GDOT(acc_, gbase_, hv_, qi_) { \
    uint4 wv = wlds[(gbase_ + qi_)*32 + j]; \
    acc_ = __builtin_amdgcn_fdot2(u2h(hv_.x), u2h(wv.x), acc_, false); \
    acc_ = __builtin_amdgcn_fdot2(u2h(hv_.y), u2h(wv.y), acc_, false); \
    acc_ = __builtin_amdgcn_fdot2(u2h(hv_.z), u2h(wv.z), acc_, false); \
    acc_ = __builtin_amdgcn_fdot2(u2h(hv_.w), u2h(wv.w), acc_, false); }
#define PF(L_) { \
    const unsigned* g16 = G16 + (L_)*48; \
    half2v zr = u2h(g16[j]); nz=(float)zr.x; nr=(float)zr.y; \
    half2v nw = u2h(g16[32+(j>>1)]); nn = (j&1)? (float)nw.y : (float)nw.x; }
#define HOP(T_) { \
    asm volatile("" ::: "memory"); \
    const uint4* hp = (const uint4*)&hsh[wslot][half*16]; \
    uint4 h0 = hp[0], h1 = hp[1], h2 = hp[2], h3 = hp[3]; \
    float az=0.f, ar=0.f, an=0.f; \
    GDOT(az, 0, h0, 0) GDOT(az, 0, h1, 1) GDOT(az, 0, h2, 2) GDOT(az, 0, h3, 3) \
    GDOT(ar, 4, h0, 0) GDOT(ar, 4, h1, 1) GDOT(ar, 4, h2, 2) GDOT(ar, 4, h3, 3) \
    GDOT(an, 8, h0, 0) GDOT(an, 8, h1, 1) GDOT(an, 8, h2, 2) GDOT(an, 8, h3, 3) \
    float z = sig_(cz + az); \
    float r = sig_(cr + ar); \
    float n = tanh_(cn + r*(an + bn)); \
    hj = z*hj + (1.0f-z)*n; \
    float oth = dpp_x1(hj); \
    unsigned pk = pkrtz(hj, oth); \
    if (wr){ hsh[wslot][half*16 + (j>>1)] = pk; seq16[(p*HN+T_)*16 + (j>>1)] = pk; } \
    cz = nz; cr = nr; cn = nn; }

    PF(la.y) HOP(0)
    PF(la.z) HOP(1)
    PF(la.w) HOP(2)
    PF(lb.x) HOP(3)
    PF(lb.y) HOP(4)
    PF(lb.z) HOP(5)
    PF(lb.w) HOP(6)
    HOP(7)
#undef PF
#undef HOP
#undef GDOT
    path_state[p*SSN + j] = hj;
}

// ---------------- queue GRU: 2-wave gather + f16 dot2, f16 state -------------
__global__ __launch_bounds__(256) void k_queue_gru(
    const unsigned* __restrict__ seq16, const int* __restrict__ p2l,
    const unsigned* __restrict__ wx16, const unsigned* __restrict__ wh16,
    const float* __restrict__ bi, const float* __restrict__ bhb,
    unsigned* __restrict__ qstate16)
{
    __shared__ float red[2][DEGN][SSN+1];
    __shared__ unsigned xpk_lds[2][16];
    int tid  = threadIdx.x;
    int wv   = tid >> 6;
    int slot = wv >> 1;
    int wp   = wv & 1;
    int lane = tid & 63;
    int r    = (lane & 31) + (wp << 5);
    int half = lane >> 5;
    int l = __builtin_amdgcn_readfirstlane(blockIdx.x*2 + slot);   // 4000*2 == 8000
    int pp  = p2l[(l*DEGN + r)*2 + 0];
    int pos = p2l[(l*DEGN + r)*2 + 1];
    const uint4* row = (const uint4*)(seq16 + (pp*HN + pos - 1)*16 + half*8);
    uint4 v0 = row[0], v1 = row[1];
    float* dst = &red[slot][r][16*half];
    {
        half2v a,b;
        a=u2h(v0.x); b=u2h(v0.y); dst[ 0]=(float)a.x; dst[ 1]=(float)a.y; dst[ 2]=(float)b.x; dst[ 3]=(float)b.y;
        a=u2h(v0.z); b=u2h(v0.w); dst[ 4]=(float)a.x; dst[ 5]=(float)a.y; dst[ 6]=(float)b.x; dst[ 7]=(float)b.y;
        a=u2h(v1.x); b=u2h(v1.y); dst[ 8]=(float)a.x; dst[ 9]=(float)a.y; dst[10]=(float)b.x; dst[11]=(float)b.y;
        a=u2h(v1.z); b=u2h(v1.w); dst[12]=(float)a.x; dst[13]=(float)a.y; dst[14]=(float)b.x; dst[15]=(float)b.y;
    }
    __syncthreads();
    if (wp) return;                          // gather-only wave retires
    int j = lane & 31;
    int base = (lane < 32) ? 0 : 32;
    float xs = 0.f;
    #pragma unroll
    for (int dd=0; dd<32; dd++) xs += red[slot][base+dd][j];
    xs = xhalf_sum(xs);
    {
        float oth = dpp_x1(xs);
        unsigned pkx = pkrtz(xs, oth);
        if (lane < 32 && !(lane & 1)) xpk_lds[slot][j>>1] = pkx;
    }
    unsigned hpk[16];
    {
        const uint4* h4 = (const uint4*)(qstate16 + l*16);
        #pragma unroll
        for (int q=0;q<4;q++){ uint4 v=h4[q]; hpk[4*q]=v.x; hpk[4*q+1]=v.y; hpk[4*q+2]=v.z; hpk[4*q+3]=v.w; }
    }
    half2v hw = u2h(hpk[j>>1]);
    float hj = (j & 1) ? (float)hw.y : (float)hw.x;
    unsigned xq[16];
    {
        asm volatile("" ::: "memory");
        const uint4* xl = (const uint4*)xpk_lds[slot];
        #pragma unroll
        for (int q=0;q<4;q++){ uint4 v=xl[q]; xq[4*q]=v.x; xq[4*q+1]=v.y; xq[4*q+2]=v.z; xq[4*q+3]=v.w; }
    }
    float az = bi[j] + bhb[j];
    float ar = bi[SSN+j] + bhb[SSN+j];
    float xn = bi[2*SSN+j];
    float hn = bhb[2*SSN+j];
    #pragma unroll
    for (int m=0;m<16;m++){
        uint4 wx4 = ((const uint4*)wx16)[m*32 + j];
        uint4 wh4 = ((const uint4*)wh16)[m*32 + j];
        az = __builtin_amdgcn_fdot2(u2h(xq[m]),  u2h(wx4.x), az, false);
        ar = __builtin_amdgcn_fdot2(u2h(xq[m]),  u2h(wx4.y), ar, false);
        xn = __builtin_amdgcn_fdot2(u2h(xq[m]),  u2h(wx4.z), xn, false);
        az = __builtin_amdgcn_fdot2(u2h(hpk[m]), u2h(wh4.x), az, false);
        ar = __builtin_amdgcn_fdot2(u2h(hpk[m]), u2h(wh4.y), ar, false);
        hn = __builtin_amdgcn_fdot2(u2h(hpk[m]), u2h(wh4.z), hn, false);
    }
    float z = sig_(az), r2 = sig_(ar);
    float n = tanh_(xn + r2*hn);
    float outv = z*hj + (1.0f-z)*n;
    float oth = dpp_x1(outv);
    if (lane < 32 && !(lane & 1))
        qstate16[l*16 + (j>>1)] = pkrtz(outv, oth);
}

// ---------------- link GRU + next-iteration G16: f16 state, scalar rows ------
__global__ __launch_bounds__(256) void k_link_gru(
    const unsigned* __restrict__ qstate16, const int* __restrict__ q2l,
    const unsigned* __restrict__ wx16, const unsigned* __restrict__ wh16,
    const float* __restrict__ bi, const float* __restrict__ bhb,
    const unsigned* __restrict__ pwx16, const float* __restrict__ pbi,
    const float* __restrict__ pbh,
    unsigned* __restrict__ lstate16, unsigned* __restrict__ G16)
{
    __shared__ unsigned lpk_lds[4][16];
    int wid = threadIdx.x >> 6, d = threadIdx.x & 63, j = d & 31;
    int l = __builtin_amdgcn_readfirstlane(blockIdx.x*4 + wid);
    int src = __builtin_amdgcn_readfirstlane(q2l[l]);
    unsigned xpk[16], hpk[16], qpk[16];
    {
        const uint4* x4 = (const uint4*)(qstate16 + src*16);
        const uint4* h4 = (const uint4*)(lstate16 + l*16);
        const uint4* q4 = (const uint4*)(qstate16 + l*16);
        #pragma unroll
        for (int q=0;q<4;q++){
            uint4 a=x4[q]; xpk[4*q]=a.x; xpk[4*q+1]=a.y; xpk[4*q+2]=a.z; xpk[4*q+3]=a.w;
            uint4 b=h4[q]; hpk[4*q]=b.x; hpk[4*q+1]=b.y; hpk[4*q+2]=b.z; hpk[4*q+3]=b.w;
            uint4 c=q4[q]; qpk[4*q]=c.x; qpk[4*q+1]=c.y; qpk[4*q+2]=c.z; qpk[4*q+3]=c.w;
        }
    }
    half2v hw = u2h(hpk[j>>1]);
    float hj = (j & 1) ? (float)hw.y : (float)hw.x;
    float az = bi[j]+bhb[j], ar = bi[SSN+j]+bhb[SSN+j];
    float xn = bi[2*SSN+j], hn = bhb[2*SSN+j];
    #pragma unroll
    for (int m=0;m<16;m++){
        uint4 wx4 = ((const uint4*)wx16)[m*32 + j];
        uint4 wh4 = ((const uint4*)wh16)[m*32 + j];
        az = __builtin_amdgcn_fdot2(u2h(xpk[m]), u2h(wx4.x), az, false);
        ar = __builtin_amdgcn_fdot2(u2h(xpk[m]), u2h(wx4.y), ar, false);
        xn = __builtin_amdgcn_fdot2(u2h(xpk[m]), u2h(wx4.z), xn, false);
        az = __builtin_amdgcn_fdot2(u2h(hpk[m]), u2h(wh4.x), az, false);
        ar = __builtin_amdgcn_fdot2(u2h(hpk[m]), u2h(wh4.y), ar, false);
        hn = __builtin_amdgcn_fdot2(u2h(hpk[m]), u2h(wh4.z), hn, false);
    }
    float z = sig_(az), r = sig_(ar);
    float n = tanh_(xn + r*hn);
    float outv = z*hj + (1.0f-z)*n;
    {
        float oth = dpp_x1(outv);
        unsigned pko = pkrtz(outv, oth);
        if (d < 32 && !(d & 1)){ lstate16[l*16 + (j>>1)] = pko; lpk_lds[wid][j>>1] = pko; }
    }
    unsigned lpk[16];
    {
        asm volatile("" ::: "memory");
        const uint4* ll = (const uint4*)lpk_lds[wid];
        #pragma unroll
        for (int q=0;q<4;q++){ uint4 v=ll[q]; lpk[4*q]=v.x; lpk[4*q+1]=v.y; lpk[4*q+2]=v.z; lpk[4*q+3]=v.w; }
    }
    float a0 = pbi[j]+pbh[j], a1 = pbi[SSN+j]+pbh[SSN+j], a2 = pbi[2*SSN+j];
    #pragma unroll
    for (int m=0;m<32;m++){
        uint4 wv4 = ((const uint4*)pwx16)[m*32 + j];
        unsigned xm = (m < 16) ? qpk[m] : lpk[m-16];
        a0 = __builtin_amdgcn_fdot2(u2h(xm), u2h(wv4.x), a0, false);
        a1 = __builtin_amdgcn_fdot2(u2h(xm), u2h(wv4.y), a1, false);
        a2 = __builtin_amdgcn_fdot2(u2h(xm), u2h(wv4.z), a2, false);
    }
    if (d < 32){
        G16[l*48 + j] = pkrtz(a0, a1);
        float a2o = dpp_x1(a2);
        if (!(d & 1)) G16[l*48 + 32 + (j>>1)] = pkrtz(a2, a2o);
    }
}

// ---------------- readout: thread per (path, hop), f16 seq in ----------------
__global__ __launch_bounds__(256, 4) void k_readout(
    const unsigned* __restrict__ seq16, const int* __restrict__ l2p,
    const float* __restrict__ cap, const float* __restrict__ ft,
    const float* __restrict__ fpk,
    const float* __restrict__ w1, const float* __restrict__ b1,
    const float* __restrict__ w2, const float* __restrict__ b2,
    const float* __restrict__ w3, const float* __restrict__ b3,
    float* __restrict__ out)
{
    int g = blockIdx.x*256 + threadIdx.x;
    int p = g >> 3, t = g & 7;
    if (p >= PN) p = PN-1;               // tail: duplicate same-value writes, benign
    int lk = l2p[p*HN + t];
    const uint4* s4 = (const uint4*)(seq16 + (p*HN+t)*16);
    float sv[SSN];
    #pragma unroll
    for (int q=0;q<4;q++){
        uint4 v = s4[q];
        half2v a=u2h(v.x), b=u2h(v.y), c=u2h(v.z), e=u2h(v.w);
        sv[8*q+0]=(float)a.x; sv[8*q+1]=(float)a.y;
        sv[8*q+2]=(float)b.x; sv[8*q+3]=(float)b.y;
        sv[8*q+4]=(float)c.x; sv[8*q+5]=(float)c.y;
        sv[8*q+6]=(float)e.x; sv[8*q+7]=(float)e.y;
    }
    float h1[16];
    #pragma unroll
    for (int j=0;j<16;j++) h1[j] = b1[j];
    #pragma unroll
    for (int k=0;k<SSN;k++){
        float vk = sv[k];
        #pragma unroll
        for (int j=0;j<16;j++) h1[j] += vk*w1[k*16+j];
    }
    #pragma unroll
    for (int j=0;j<16;j++) h1[j] = fmaxf(h1[j], 0.f);
    float h2[16];
    #pragma unroll
    for (int j=0;j<16;j++) h2[j] = b2[j];
    #pragma unroll
    for (int k=0;k<16;k++){
        float hk = h1[k];
        #pragma unroll
        for (int j=0;j<16;j++) h2[j] += hk*w2[k*16+j];
    }
    float occ = b3[0];
    #pragma unroll
    for (int k=0;k<16;k++) occ += fmaxf(h2[k], 0.f)*w3[k];
    float icg = rcp_(cap[lk]) * 1e-9f;
    float qd  = occ * icg;
    float inv = icg;
    qd  += __shfl_xor(qd, 1);  inv += __shfl_xor(inv, 1);
    qd  += __shfl_xor(qd, 2);  inv += __shfl_xor(inv, 2);
    qd  += __shfl_xor(qd, 4);  inv += __shfl_xor(inv, 4);
    if ((threadIdx.x & 7) == 0)
        out[p] = qd + ft[p]*rcp_(fpk[p])*inv;
}

extern "C" void kernel_launch(void* const* d_in, const int* in_sizes, int n_in,
                              void* d_out, int out_size, void* d_ws, size_t ws_size,
                              hipStream_t stream)
{
    (void)in_sizes; (void)n_in; (void)out_size; (void)ws_size;
    const float* ft    = (const float*)d_in[0];
    const float* fpk   = (const float*)d_in[1];
    const float* flam  = (const float*)d_in[2];
    const float* fob   = (const float*)d_in[3];
    const float* fon   = (const float*)d_in[4];
    const float* foff  = (const float*)d_in[5];
    const float* cap   = (const float*)d_in[6];
    const float* pe_w1 = (const float*)d_in[7];
    const float* pe_b1 = (const float*)d_in[8];
    const float* pe_w2 = (const float*)d_in[9];
    const float* pe_b2 = (const float*)d_in[10];
    const float* le_w1 = (const float*)d_in[11];
    const float* le_b1 = (const float*)d_in[12];
    const float* le_w2 = (const float*)d_in[13];
    const float* le_b2 = (const float*)d_in[14];
    const float* qe_w1 = (const float*)d_in[15];
    const float* qe_b1 = (const float*)d_in[16];
    const float* qe_w2 = (const float*)d_in[17];
    const float* qe_b2 = (const float*)d_in[18];
    const float* pWx   = (const float*)d_in[19];
    const float* pWh   = (const float*)d_in[20];
    const float* pbi   = (const float*)d_in[21];
    const float* pbh   = (const float*)d_in[22];
    const float* qWx   = (const float*)d_in[23];
    const float* qWh   = (const float*)d_in[24];
    const float* qbi   = (const float*)d_in[25];
    const float* qbh   = (const float*)d_in[26];
    const float* lWx   = (const float*)d_in[27];
    const float* lWh   = (const float*)d_in[28];
    const float* lbi   = (const float*)d_in[29];
    const float* lbh   = (const float*)d_in[30];
    const float* ro_w1 = (const float*)d_in[31];
    const float* ro_b1 = (const float*)d_in[32];
    const float* ro_w2 = (const float*)d_in[33];
    const float* ro_b2 = (const float*)d_in[34];
    const float* ro_w3 = (const float*)d_in[35];
    const float* ro_b3 = (const float*)d_in[36];
    const int* fdist = (const int*)d_in[37];
    const int* btype = (const int*)d_in[38];
    const int* l2p   = (const int*)d_in[39];
    const int* p2l   = (const int*)d_in[40];
    const int* q2l   = (const int*)d_in[41];

    float* ws = (float*)d_ws;
    unsigned* pWhp16   = (unsigned*)(ws + OFF_PWHP);
    float* path_state  = ws + OFF_PATH;
    unsigned* seq16    = (unsigned*)(ws + OFF_SEQ);
    unsigned* qwx16    = (unsigned*)(ws + OFF_QWX16);
    unsigned* qwh16    = (unsigned*)(ws + OFF_QWH16);
    unsigned* lwx16    = (unsigned*)(ws + OFF_LWX16);
    unsigned* lwh16    = (unsigned*)(ws + OFF_LWH16);
    unsigned* pwx16    = (unsigned*)(ws + OFF_PWX16);
    unsigned* qstate16 = (unsigned*)(ws + OFF_QST);
    unsigned* lstate16 = (unsigned*)(ws + OFF_LST);
    unsigned* G16      = (unsigned*)(ws + OFF_G);

    k_startup<<<2250, 256, 0, stream>>>(pWh, pWx, qWx, qWh, lWx, lWh, ws,
                                        ft, fpk, flam, fob, fon, foff, fdist,
                                        pe_w1, pe_b1, pe_w2, pe_b2, path_state,
                                        cap, p2l, btype,
                                        le_w1, le_b1, le_w2, le_b2,
                                        qe_w1, qe_b1, qe_w2, qe_b2,
                                        pbi, pbh, lstate16, qstate16, G16);
    for (int it = 0; it < 7; ++it){
        k_path_gru<<<PN/8, 256, 0, stream>>>(G16, l2p, pWhp16, pbh, path_state, seq16);
        k_queue_gru<<<LN/2, 256, 0, stream>>>(seq16, p2l, qwx16, qwh16, qbi, qbh, qstate16);
        k_link_gru<<<LN/4, 256, 0, stream>>>(qstate16, q2l, lwx16, lwh16, lbi, lbh,
                                             pwx16, pbi, pbh, lstate16, G16);
    }
    // 8th iteration: queue/link outputs are dead (readout uses only seq)
    k_path_gru<<<PN/8, 256, 0, stream>>>(G16, l2p, pWhp16, pbh, path_state, seq16);
    k_readout<<<(PN*HN+255)/256, 256, 0, stream>>>(seq16, l2p, cap, ft, fpk,
                                                   ro_w1, ro_b1, ro_w2, ro_b2, ro_w3, ro_b3,
                                                   (float*)d_out);
}